// Round 1
// baseline (5420.498 us; speedup 1.0000x reference)
//
#include <hip/hip_runtime.h>
#include <hip/hip_bf16.h>

// FusedTriangleMultiplicationOpti — fp32 baseline, 3 fused kernels.
// ws layout: left [NP][C] f32 | right [NP][C] f32 | xh [NP][C] bf16  (total 336 MB)

constexpr int TN = 512;
constexpr int TC = 128;
constexpr int TNP = TN * TN;
constexpr float TEPS = 1e-5f;

__device__ __forceinline__ float wredsum(float v) {
#pragma unroll
    for (int off = 32; off > 0; off >>= 1) v += __shfl_xor(v, off);
    return v;
}

__device__ __forceinline__ float sigmoidf(float x) {
    return 1.0f / (1.0f + __expf(-x));
}

// -------- Kernel A: LN + dual GEMM (proj & gate) + mask*sigmoid gating --------
extern "C" __global__ __launch_bounds__(256)
void k_ln_proj(const float* __restrict__ act, const float* __restrict__ mask,
               const float* __restrict__ lnw, const float* __restrict__ lnb,
               const float* __restrict__ proj_w, const float* __restrict__ proj_b,
               const float* __restrict__ gate_w, const float* __restrict__ gate_b,
               float* __restrict__ left, float* __restrict__ right,
               __hip_bfloat16* __restrict__ xh)
{
    __shared__ float xs[32 * 129];   // +1-pad stride: strided row reads hit distinct banks
    __shared__ float wp[32 * 129];
    __shared__ float wg[32 * 129];
    __shared__ float msk[32];

    const int t = threadIdx.x;
    const int p0 = blockIdx.x * 32;
    const int lane = t & 63;
    const int wv = t >> 6;

    // LN phase: each wave handles one position per iteration (2 elems/lane)
#pragma unroll
    for (int it = 0; it < 8; ++it) {
        const int pl = it * 4 + wv;
        const int p = p0 + pl;
        const float a0 = act[(size_t)p * TC + lane];
        const float a1 = act[(size_t)p * TC + 64 + lane];
        const float mu = wredsum(a0 + a1) * (1.0f / 128.0f);
        const float d0 = a0 - mu, d1 = a1 - mu;
        const float var = wredsum(d0 * d0 + d1 * d1) * (1.0f / 128.0f);
        const float rs = rsqrtf(var + TEPS);
        const float x0 = d0 * rs * lnw[lane] + lnb[lane];
        const float x1 = d1 * rs * lnw[64 + lane] + lnb[64 + lane];
        xs[pl * 129 + lane] = x0;
        xs[pl * 129 + 64 + lane] = x1;
        xh[(size_t)p * TC + lane] = __float2bfloat16(x0);
        xh[(size_t)p * TC + 64 + lane] = __float2bfloat16(x1);
    }
    if (t < 32) msk[t] = mask[p0 + t];

    const int dg = t & 15;   // 16 dim-groups x 2 dims
    const int pg = t >> 4;   // 16 pos-groups x 2 positions
    const float* xr0 = &xs[(pg * 2 + 0) * 129];
    const float* xr1 = &xs[(pg * 2 + 1) * 129];

    for (int nc = 0; nc < 8; ++nc) {   // 8 chunks of 32 output dims (512 total)
        __syncthreads();   // nc==0: covers LN-phase LDS writes; else guards w overwrite
        for (int idx = t; idx < 32 * 128; idx += 256) {
            const int r = idx >> 7, k = idx & 127;
            wp[r * 129 + k] = proj_w[(nc * 32 + r) * TC + k];
            wg[r * 129 + k] = gate_w[(nc * 32 + r) * TC + k];
        }
        __syncthreads();

        const float* wp0 = &wp[(dg * 2 + 0) * 129];
        const float* wp1 = &wp[(dg * 2 + 1) * 129];
        const float* wg0 = &wg[(dg * 2 + 0) * 129];
        const float* wg1 = &wg[(dg * 2 + 1) * 129];
        float aP00 = 0.f, aP01 = 0.f, aP10 = 0.f, aP11 = 0.f;
        float aG00 = 0.f, aG01 = 0.f, aG10 = 0.f, aG11 = 0.f;
#pragma unroll 4
        for (int k = 0; k < TC; ++k) {
            const float x0 = xr0[k], x1 = xr1[k];
            const float pa = wp0[k], pb = wp1[k];
            const float ga = wg0[k], gb = wg1[k];
            aP00 += x0 * pa; aP01 += x0 * pb;
            aP10 += x1 * pa; aP11 += x1 * pb;
            aG00 += x0 * ga; aG01 += x0 * gb;
            aG10 += x1 * ga; aG11 += x1 * gb;
        }

        const float accP[2][2] = {{aP00, aP01}, {aP10, aP11}};
        const float accG[2][2] = {{aG00, aG01}, {aG10, aG11}};
#pragma unroll
        for (int pp = 0; pp < 2; ++pp) {
            const int pl = pg * 2 + pp;
            const int p = p0 + pl;
            const float m = msk[pl];
#pragma unroll
            for (int dd = 0; dd < 2; ++dd) {
                const int d = nc * 32 + dg * 2 + dd;
                const float pv = accP[pp][dd] + proj_b[d];
                const float gv = accG[pp][dd] + gate_b[d];
                const float val = m * pv * sigmoidf(gv);
                if (d < TC) left[(size_t)p * TC + d] = val;
                else        right[(size_t)p * TC + (d - TC)] = val;
            }
        }
    }
}

// -------- Kernel B: out[i,j,c] = sum_k left[i,k,c]*right[j,k,c] --------
// c is the lane dim (coalesced, no transposes). 32i x 32j x 32c tile per block.
extern "C" __global__ __launch_bounds__(256)
void k_tri(const float* __restrict__ left, const float* __restrict__ right,
           float* __restrict__ out)
{
    __shared__ float Ls[8 * 32 * 32];   // [k][i][c]
    __shared__ float Rs[8 * 32 * 32];   // [k][j][c]

    const int t = threadIdx.x;
    const int cc = t & 31;
    const int q = t >> 5;               // 8 i-groups x 4 rows
    const int i0 = blockIdx.x * 32;
    const int j0 = blockIdx.y * 32;
    const int c0 = blockIdx.z * 32;

    float acc[4][32];
#pragma unroll
    for (int a = 0; a < 4; ++a)
#pragma unroll
        for (int b = 0; b < 32; ++b) acc[a][b] = 0.0f;

    const float* lbase = left + (size_t)i0 * TN * TC + c0;
    const float* rbase = right + (size_t)j0 * TN * TC + c0;

    for (int k0 = 0; k0 < TN; k0 += 8) {
        __syncthreads();
#pragma unroll
        for (int e = 0; e < 32; ++e) {
            const int idx = e * 256 + t;          // = lk*1024 + li*32 + lc
            const int lc = idx & 31;
            const int li = (idx >> 5) & 31;
            const int lk = idx >> 10;
            Ls[idx] = lbase[((size_t)li * TN + (k0 + lk)) * TC + lc];
            Rs[idx] = rbase[((size_t)li * TN + (k0 + lk)) * TC + lc];
        }
        __syncthreads();
#pragma unroll
        for (int kk = 0; kk < 8; ++kk) {
            float Lf[4];
#pragma unroll
            for (int ii = 0; ii < 4; ++ii)
                Lf[ii] = Ls[kk * 1024 + (q * 4 + ii) * 32 + cc];
#pragma unroll
            for (int j = 0; j < 32; ++j) {
                const float rv = Rs[kk * 1024 + j * 32 + cc];
#pragma unroll
                for (int ii = 0; ii < 4; ++ii)
                    acc[ii][j] += Lf[ii] * rv;
            }
        }
    }

#pragma unroll
    for (int ii = 0; ii < 4; ++ii) {
        const int i = i0 + q * 4 + ii;
#pragma unroll
        for (int j = 0; j < 32; ++j)
            out[((size_t)i * TN + (j0 + j)) * TC + c0 + cc] = acc[ii][j];
    }
}

// -------- Kernel C: LN(tri) + out-proj + gl-gate, in-place on d_out --------
extern "C" __global__ __launch_bounds__(256)
void k_out_proj(float* io, const __hip_bfloat16* __restrict__ xh,
                const float* __restrict__ cnw, const float* __restrict__ cnb,
                const float* __restrict__ outp_w, const float* __restrict__ outp_b,
                const float* __restrict__ gl_w, const float* __restrict__ gl_b)
{
    __shared__ float ys[32 * 129];
    __shared__ __hip_bfloat16 hs[32 * 130];
    __shared__ float wo[32 * 129];
    __shared__ float wgl[32 * 129];

    const int t = threadIdx.x;
    const int p0 = blockIdx.x * 32;
    const int lane = t & 63;
    const int wv = t >> 6;

#pragma unroll
    for (int it = 0; it < 8; ++it) {
        const int pl = it * 4 + wv;
        const int p = p0 + pl;
        const float a0 = io[(size_t)p * TC + lane];
        const float a1 = io[(size_t)p * TC + 64 + lane];
        const float mu = wredsum(a0 + a1) * (1.0f / 128.0f);
        const float d0 = a0 - mu, d1 = a1 - mu;
        const float var = wredsum(d0 * d0 + d1 * d1) * (1.0f / 128.0f);
        const float rs = rsqrtf(var + TEPS);
        ys[pl * 129 + lane]      = d0 * rs * cnw[lane] + cnb[lane];
        ys[pl * 129 + 64 + lane] = d1 * rs * cnw[64 + lane] + cnb[64 + lane];
        hs[pl * 130 + lane]      = xh[(size_t)p * TC + lane];
        hs[pl * 130 + 64 + lane] = xh[(size_t)p * TC + 64 + lane];
    }

    const int dg = t & 15;
    const int pg = t >> 4;
    const float* yr0 = &ys[(pg * 2 + 0) * 129];
    const float* yr1 = &ys[(pg * 2 + 1) * 129];
    const __hip_bfloat16* hr0 = &hs[(pg * 2 + 0) * 130];
    const __hip_bfloat16* hr1 = &hs[(pg * 2 + 1) * 130];

    for (int nc = 0; nc < 4; ++nc) {   // 4 chunks of 32 output dims (128 total)
        __syncthreads();
        for (int idx = t; idx < 32 * 128; idx += 256) {
            const int r = idx >> 7, k = idx & 127;
            wo[r * 129 + k]  = outp_w[(nc * 32 + r) * TC + k];
            wgl[r * 129 + k] = gl_w[(nc * 32 + r) * TC + k];
        }
        __syncthreads();

        const float* wo0 = &wo[(dg * 2 + 0) * 129];
        const float* wo1 = &wo[(dg * 2 + 1) * 129];
        const float* wl0 = &wgl[(dg * 2 + 0) * 129];
        const float* wl1 = &wgl[(dg * 2 + 1) * 129];
        float aO00 = 0.f, aO01 = 0.f, aO10 = 0.f, aO11 = 0.f;
        float aG00 = 0.f, aG01 = 0.f, aG10 = 0.f, aG11 = 0.f;
#pragma unroll 4
        for (int k = 0; k < TC; ++k) {
            const float y0 = yr0[k], y1 = yr1[k];
            const float h0 = __bfloat162float(hr0[k]);
            const float h1 = __bfloat162float(hr1[k]);
            const float o0 = wo0[k], o1 = wo1[k];
            const float l0 = wl0[k], l1 = wl1[k];
            aO00 += y0 * o0; aO01 += y0 * o1;
            aO10 += y1 * o0; aO11 += y1 * o1;
            aG00 += h0 * l0; aG01 += h0 * l1;
            aG10 += h1 * l0; aG11 += h1 * l1;
        }
        const float accO[2][2] = {{aO00, aO01}, {aO10, aO11}};
        const float accG[2][2] = {{aG00, aG01}, {aG10, aG11}};
#pragma unroll
        for (int pp = 0; pp < 2; ++pp) {
            const int p = p0 + pg * 2 + pp;
#pragma unroll
            for (int dd = 0; dd < 2; ++dd) {
                const int d = nc * 32 + dg * 2 + dd;
                const float o = accO[pp][dd] + outp_b[d];
                const float g = accG[pp][dd] + gl_b[d];
                io[(size_t)p * TC + d] = o * sigmoidf(g);
            }
        }
    }
}

extern "C" void kernel_launch(void* const* d_in, const int* in_sizes, int n_in,
                              void* d_out, int out_size, void* d_ws, size_t ws_size,
                              hipStream_t stream)
{
    const float* act    = (const float*)d_in[0];
    const float* mask   = (const float*)d_in[1];
    const float* lnw    = (const float*)d_in[2];
    const float* lnb    = (const float*)d_in[3];
    const float* proj_w = (const float*)d_in[4];
    const float* proj_b = (const float*)d_in[5];
    const float* gate_w = (const float*)d_in[6];
    const float* gate_b = (const float*)d_in[7];
    const float* cnw    = (const float*)d_in[8];
    const float* cnb    = (const float*)d_in[9];
    const float* outp_w = (const float*)d_in[10];
    const float* outp_b = (const float*)d_in[11];
    const float* gl_w   = (const float*)d_in[12];
    const float* gl_b   = (const float*)d_in[13];

    float* left  = (float*)d_ws;
    float* right = left + (size_t)TNP * TC;
    __hip_bfloat16* xh = (__hip_bfloat16*)(right + (size_t)TNP * TC);
    float* out = (float*)d_out;

    k_ln_proj<<<TNP / 32, 256, 0, stream>>>(act, mask, lnw, lnb, proj_w, proj_b,
                                            gate_w, gate_b, left, right, xh);
    k_tri<<<dim3(TN / 32, TN / 32, TC / 32), 256, 0, stream>>>(left, right, out);
    k_out_proj<<<TNP / 32, 256, 0, stream>>>(out, xh, cnw, cnb,
                                             outp_w, outp_b, gl_w, gl_b);
}

// Round 3
// 1535.651 us; speedup vs baseline: 3.5298x; 3.5298x over previous
//
#include <hip/hip_runtime.h>
#include <hip/hip_bf16.h>

// FusedTriangleMultiplicationOpti — round 3: MFMA triangle einsum (nc-loop fix).
// ws layout: lt bf16 [C][N*N] | rt bf16 [C][N*N] | xh bf16 [N*N][C] | tri f32 [C][N*N]
//   = 64 + 64 + 64 + 128 MB = 320 MB

constexpr int TN = 512;
constexpr int TC = 128;
constexpr int TNP = TN * TN;
constexpr float TEPS = 1e-5f;

typedef __attribute__((ext_vector_type(8))) short s8b;   // 8 bf16 (4 VGPRs)
typedef __attribute__((ext_vector_type(4))) float f4;    // 4 fp32 acc

__device__ __forceinline__ float wredsum(float v) {
#pragma unroll
    for (int off = 32; off > 0; off >>= 1) v += __shfl_xor(v, off);
    return v;
}

__device__ __forceinline__ float sigmoidf(float x) {
    return 1.0f / (1.0f + __expf(-x));
}

// -------- Kernel A: LN + dual GEMM (proj & gate) + mask*sigmoid gating --------
// Writes lt/rt in [c][p] bf16 layout (p = i*512 + k) via LDS transpose.
extern "C" __global__ __launch_bounds__(256)
void k_ln_proj(const float* __restrict__ act, const float* __restrict__ mask,
               const float* __restrict__ lnw, const float* __restrict__ lnb,
               const float* __restrict__ proj_w, const float* __restrict__ proj_b,
               const float* __restrict__ gate_w, const float* __restrict__ gate_b,
               __hip_bfloat16* __restrict__ lt, __hip_bfloat16* __restrict__ rt,
               __hip_bfloat16* __restrict__ xh)
{
    __shared__ float xs[32 * 129];
    __shared__ float wp[32 * 129];
    __shared__ float wg[32 * 129];
    __shared__ __hip_bfloat16 tls[32 * 34];   // [d_local][p_local] transpose tile
    __shared__ float msk[32];

    const int t = threadIdx.x;
    const int p0 = blockIdx.x * 32;
    const int lane = t & 63;
    const int wv = t >> 6;

#pragma unroll
    for (int it = 0; it < 8; ++it) {
        const int pl = it * 4 + wv;
        const int p = p0 + pl;
        const float a0 = act[(size_t)p * TC + lane];
        const float a1 = act[(size_t)p * TC + 64 + lane];
        const float mu = wredsum(a0 + a1) * (1.0f / 128.0f);
        const float d0 = a0 - mu, d1 = a1 - mu;
        const float var = wredsum(d0 * d0 + d1 * d1) * (1.0f / 128.0f);
        const float rs = rsqrtf(var + TEPS);
        const float x0 = d0 * rs * lnw[lane] + lnb[lane];
        const float x1 = d1 * rs * lnw[64 + lane] + lnb[64 + lane];
        xs[pl * 129 + lane] = x0;
        xs[pl * 129 + 64 + lane] = x1;
        xh[(size_t)p * TC + lane] = __float2bfloat16(x0);
        xh[(size_t)p * TC + 64 + lane] = __float2bfloat16(x1);
    }
    if (t < 32) msk[t] = mask[p0 + t];

    const int dg = t & 15;   // 16 dim-groups x 2 dims
    const int pg = t >> 4;   // 16 pos-groups x 2 positions
    const float* xr0 = &xs[(pg * 2 + 0) * 129];
    const float* xr1 = &xs[(pg * 2 + 1) * 129];

    for (int nc = 0; nc < 8; ++nc) {   // 8 chunks of 32 output dims (2C = 256 total)
        __syncthreads();   // guards w/tls overwrite vs previous use
        for (int idx = t; idx < 32 * 128; idx += 256) {
            const int r = idx >> 7, k = idx & 127;
            wp[r * 129 + k] = proj_w[(nc * 32 + r) * TC + k];
            wg[r * 129 + k] = gate_w[(nc * 32 + r) * TC + k];
        }
        __syncthreads();

        const float* wp0 = &wp[(dg * 2 + 0) * 129];
        const float* wp1 = &wp[(dg * 2 + 1) * 129];
        const float* wg0 = &wg[(dg * 2 + 0) * 129];
        const float* wg1 = &wg[(dg * 2 + 1) * 129];
        float aP00 = 0.f, aP01 = 0.f, aP10 = 0.f, aP11 = 0.f;
        float aG00 = 0.f, aG01 = 0.f, aG10 = 0.f, aG11 = 0.f;
#pragma unroll 4
        for (int k = 0; k < TC; ++k) {
            const float x0 = xr0[k], x1 = xr1[k];
            const float pa = wp0[k], pb = wp1[k];
            const float ga = wg0[k], gb = wg1[k];
            aP00 += x0 * pa; aP01 += x0 * pb;
            aP10 += x1 * pa; aP11 += x1 * pb;
            aG00 += x0 * ga; aG01 += x0 * gb;
            aG10 += x1 * ga; aG11 += x1 * gb;
        }

        const float accP[2][2] = {{aP00, aP01}, {aP10, aP11}};
        const float accG[2][2] = {{aG00, aG01}, {aG10, aG11}};
#pragma unroll
        for (int pp = 0; pp < 2; ++pp) {
            const int pl = pg * 2 + pp;
            const float m = msk[pl];
#pragma unroll
            for (int dd = 0; dd < 2; ++dd) {
                const float pv = accP[pp][dd] + proj_b[nc * 32 + dg * 2 + dd];
                const float gv = accG[pp][dd] + gate_b[nc * 32 + dg * 2 + dd];
                const float val = m * pv * sigmoidf(gv);
                tls[(dg * 2 + dd) * 34 + pl] = __float2bfloat16(val);
            }
        }
        __syncthreads();
        // transposed readout: 64 B-coalesced bf16 writes into [c][p] layout
        {
            const int pl = t & 31;
            const int dl = (t >> 5) * 4;
            const int pglob = p0 + pl;
#pragma unroll
            for (int dd = 0; dd < 4; ++dd) {
                const int d = nc * 32 + dl + dd;
                const __hip_bfloat16 v = tls[(dl + dd) * 34 + pl];
                if (d < TC) lt[(size_t)d * TNP + pglob] = v;
                else        rt[(size_t)(d - TC) * TNP + pglob] = v;
            }
        }
    }
}

// -------- Kernel B: per-c 512x512x512 NT-GEMM, bf16 MFMA --------
// tri[c][i][j] = sum_k lt[c][i][k] * rt[c][j][k]
extern "C" __global__ __launch_bounds__(256)
void k_tri_mfma(const __hip_bfloat16* __restrict__ lt,
                const __hip_bfloat16* __restrict__ rt,
                float* __restrict__ tri)
{
    __shared__ __hip_bfloat16 Als[128 * 32];   // [m][k], 64 B rows
    __shared__ __hip_bfloat16 Bls[128 * 32];   // [n][k]

    const int t = threadIdx.x;
    const int w = t >> 6, lane = t & 63;
    const int i0 = blockIdx.x * 128, j0 = blockIdx.y * 128;
    const int c = blockIdx.z;
    const int wm = w >> 1, wn = w & 1;         // wave tile (wm*64, wn*64)
    const int lh = lane & 15, lq = lane >> 4;

    const size_t cbase = (size_t)c * TNP;
    const int srow = lane >> 2;                // staging row within 16-row group
    const int scol = (lane & 3) * 8;           // staging k-offset (8 bf16 = 16 B)

    f4 acc[4][4];
#pragma unroll
    for (int mi = 0; mi < 4; ++mi)
#pragma unroll
        for (int ni = 0; ni < 4; ++ni)
            acc[mi][ni] = (f4){0.f, 0.f, 0.f, 0.f};

    for (int k0 = 0; k0 < TN; k0 += 32) {
        __syncthreads();   // previous compute done before LDS overwrite
#pragma unroll
        for (int s = 0; s < 2; ++s) {
            const int r0 = w * 32 + s * 16;    // 16 rows per call (64 lanes x 16 B)
            const __hip_bfloat16* ga = lt + cbase + (size_t)(i0 + r0 + srow) * TN + k0 + scol;
            const __hip_bfloat16* gb = rt + cbase + (size_t)(j0 + r0 + srow) * TN + k0 + scol;
            __builtin_amdgcn_global_load_lds(
                (const __attribute__((address_space(1))) unsigned*)ga,
                (__attribute__((address_space(3))) unsigned*)&Als[r0 * 32], 16, 0, 0);
            __builtin_amdgcn_global_load_lds(
                (const __attribute__((address_space(1))) unsigned*)gb,
                (__attribute__((address_space(3))) unsigned*)&Bls[r0 * 32], 16, 0, 0);
        }
        __syncthreads();   // drains vmcnt(0), loads visible

        s8b af[4], bf[4];
#pragma unroll
        for (int mi = 0; mi < 4; ++mi)
            af[mi] = *(const s8b*)&Als[(wm * 64 + mi * 16 + lh) * 32 + lq * 8];
#pragma unroll
        for (int ni = 0; ni < 4; ++ni)
            bf[ni] = *(const s8b*)&Bls[(wn * 64 + ni * 16 + lh) * 32 + lq * 8];
#pragma unroll
        for (int mi = 0; mi < 4; ++mi)
#pragma unroll
            for (int ni = 0; ni < 4; ++ni)
                acc[mi][ni] = __builtin_amdgcn_mfma_f32_16x16x32_bf16(
                    af[mi], bf[ni], acc[mi][ni], 0, 0, 0);
    }

    float* outp = tri + cbase;
#pragma unroll
    for (int mi = 0; mi < 4; ++mi) {
#pragma unroll
        for (int ni = 0; ni < 4; ++ni) {
            const f4 v = acc[mi][ni];
            const int ib = i0 + wm * 64 + mi * 16 + lq * 4;
            const int jb = j0 + wn * 64 + ni * 16 + lh;
#pragma unroll
            for (int r = 0; r < 4; ++r)
                outp[(size_t)(ib + r) * TN + jb] = v[r];
        }
    }
}

// -------- Kernel C: LN(tri) + out-proj + gl-gate --------
// Reads tri in [c][p] layout via LDS transpose; writes d_out [p][c].
extern "C" __global__ __launch_bounds__(256)
void k_out_proj(const float* __restrict__ tri, const __hip_bfloat16* __restrict__ xh,
                const float* __restrict__ cnw, const float* __restrict__ cnb,
                const float* __restrict__ outp_w, const float* __restrict__ outp_b,
                const float* __restrict__ gl_w, const float* __restrict__ gl_b,
                float* __restrict__ outb)
{
    __shared__ float ys[32 * 129];
    __shared__ __hip_bfloat16 hs[32 * 130];
    __shared__ float wo[32 * 129];
    __shared__ float wgl[32 * 129];

    const int t = threadIdx.x;
    const int p0 = blockIdx.x * 32;
    const int lane = t & 63;
    const int wv = t >> 6;

    // stage tri tile [c][p] -> ys[p][c] (coalesced 128 B reads along p)
    {
        const int pl = t & 31;
        const int ch0 = t >> 5;   // 0..7
#pragma unroll
        for (int cc = 0; cc < 16; ++cc) {
            const int ch = cc * 8 + ch0;
            ys[pl * 129 + ch] = tri[(size_t)ch * TNP + p0 + pl];
        }
    }
    __syncthreads();

    // LN in-place on ys rows + stage gate input
#pragma unroll
    for (int it = 0; it < 8; ++it) {
        const int pl = it * 4 + wv;
        const int p = p0 + pl;
        const float a0 = ys[pl * 129 + lane];
        const float a1 = ys[pl * 129 + 64 + lane];
        const float mu = wredsum(a0 + a1) * (1.0f / 128.0f);
        const float d0 = a0 - mu, d1 = a1 - mu;
        const float var = wredsum(d0 * d0 + d1 * d1) * (1.0f / 128.0f);
        const float rs = rsqrtf(var + TEPS);
        ys[pl * 129 + lane]      = d0 * rs * cnw[lane] + cnb[lane];
        ys[pl * 129 + 64 + lane] = d1 * rs * cnw[64 + lane] + cnb[64 + lane];
        hs[pl * 130 + lane]      = xh[(size_t)p * TC + lane];
        hs[pl * 130 + 64 + lane] = xh[(size_t)p * TC + 64 + lane];
    }

    const int dg = t & 15;
    const int pg = t >> 4;
    const float* yr0 = &ys[(pg * 2 + 0) * 129];
    const float* yr1 = &ys[(pg * 2 + 1) * 129];
    const __hip_bfloat16* hr0 = &hs[(pg * 2 + 0) * 130];
    const __hip_bfloat16* hr1 = &hs[(pg * 2 + 1) * 130];

    for (int nc = 0; nc < 4; ++nc) {
        __syncthreads();
        for (int idx = t; idx < 32 * 128; idx += 256) {
            const int r = idx >> 7, k = idx & 127;
            wo[r * 129 + k]  = outp_w[(nc * 32 + r) * TC + k];
            wgl[r * 129 + k] = gl_w[(nc * 32 + r) * TC + k];
        }
        __syncthreads();

        const float* wo0 = &wo[(dg * 2 + 0) * 129];
        const float* wo1 = &wo[(dg * 2 + 1) * 129];
        const float* wl0 = &wgl[(dg * 2 + 0) * 129];
        const float* wl1 = &wgl[(dg * 2 + 1) * 129];
        float aO00 = 0.f, aO01 = 0.f, aO10 = 0.f, aO11 = 0.f;
        float aG00 = 0.f, aG01 = 0.f, aG10 = 0.f, aG11 = 0.f;
#pragma unroll 4
        for (int k = 0; k < TC; ++k) {
            const float y0 = yr0[k], y1 = yr1[k];
            const float h0 = __bfloat162float(hr0[k]);
            const float h1 = __bfloat162float(hr1[k]);
            const float o0 = wo0[k], o1 = wo1[k];
            const float l0 = wl0[k], l1 = wl1[k];
            aO00 += y0 * o0; aO01 += y0 * o1;
            aO10 += y1 * o0; aO11 += y1 * o1;
            aG00 += h0 * l0; aG01 += h0 * l1;
            aG10 += h1 * l0; aG11 += h1 * l1;
        }
        const float accO[2][2] = {{aO00, aO01}, {aO10, aO11}};
        const float accG[2][2] = {{aG00, aG01}, {aG10, aG11}};
#pragma unroll
        for (int pp = 0; pp < 2; ++pp) {
            const int p = p0 + pg * 2 + pp;
#pragma unroll
            for (int dd = 0; dd < 2; ++dd) {
                const int d = nc * 32 + dg * 2 + dd;
                const float o = accO[pp][dd] + outp_b[d];
                const float g = accG[pp][dd] + gl_b[d];
                outb[(size_t)p * TC + d] = o * sigmoidf(g);
            }
        }
    }
}

extern "C" void kernel_launch(void* const* d_in, const int* in_sizes, int n_in,
                              void* d_out, int out_size, void* d_ws, size_t ws_size,
                              hipStream_t stream)
{
    const float* act    = (const float*)d_in[0];
    const float* mask   = (const float*)d_in[1];
    const float* lnw    = (const float*)d_in[2];
    const float* lnb    = (const float*)d_in[3];
    const float* proj_w = (const float*)d_in[4];
    const float* proj_b = (const float*)d_in[5];
    const float* gate_w = (const float*)d_in[6];
    const float* gate_b = (const float*)d_in[7];
    const float* cnw    = (const float*)d_in[8];
    const float* cnb    = (const float*)d_in[9];
    const float* outp_w = (const float*)d_in[10];
    const float* outp_b = (const float*)d_in[11];
    const float* gl_w   = (const float*)d_in[12];
    const float* gl_b   = (const float*)d_in[13];

    __hip_bfloat16* lt = (__hip_bfloat16*)d_ws;
    __hip_bfloat16* rt = lt + (size_t)TC * TNP;
    __hip_bfloat16* xh = rt + (size_t)TC * TNP;
    float* tri = (float*)(xh + (size_t)TNP * TC);
    float* out = (float*)d_out;

    k_ln_proj<<<TNP / 32, 256, 0, stream>>>(act, mask, lnw, lnb, proj_w, proj_b,
                                            gate_w, gate_b, lt, rt, xh);
    k_tri_mfma<<<dim3(TN / 128, TN / 128, TC), 256, 0, stream>>>(lt, rt, tri);
    k_out_proj<<<TNP / 32, 256, 0, stream>>>(tri, xh, cnw, cnb,
                                             outp_w, outp_b, gl_w, gl_b, out);
}

// Round 4
// 559.693 us; speedup vs baseline: 9.6848x; 2.7437x over previous
//
#include <hip/hip_runtime.h>
#include <hip/hip_bf16.h>

// Round 4: MFMA everywhere. ws: lt|rt|xh bf16 64MB each, tri f32 128MB, wcat/wcat2 bf16.

constexpr int TN = 512;
constexpr int TC = 128;
constexpr int TNP = TN * TN;
constexpr float TEPS = 1e-5f;
constexpr int PB = 64;               // positions per block (kernels A/C)

typedef __attribute__((ext_vector_type(8))) short s8b;   // 8 bf16
typedef __attribute__((ext_vector_type(4))) float f4;    // 4 fp32

__device__ __forceinline__ float wredsum(float v) {
#pragma unroll
    for (int off = 32; off > 0; off >>= 1) v += __shfl_xor(v, off);
    return v;
}

__device__ __forceinline__ float sigmoidf(float x) {
    return 1.0f / (1.0f + __expf(-x));
}

// fragment-permuted LDS index: A-frag (mi=p>>4, kg=k>>5) stored lane-linear so
// frag reads are ds_read_b128 at addr = base + lane*16B (conflict-free).
__device__ __forceinline__ int xidx(int p, int k) {
    return (((p >> 4) * 4 + (k >> 5)) * 64 + (((k >> 3) & 3) * 16 + (p & 15))) * 8 + (k & 7);
}

// -------- weight fp32 -> bf16 pre-convert --------
extern "C" __global__ __launch_bounds__(256)
void k_wconv(const float* __restrict__ pw, const float* __restrict__ gw,
             const float* __restrict__ ow, const float* __restrict__ glw,
             __hip_bfloat16* __restrict__ wcat, __hip_bfloat16* __restrict__ wcat2)
{
    const int idx = blockIdx.x * 256 + threadIdx.x;
    if (idx < 32768) {               // proj (256x128) + gate (256x128)
        wcat[idx] = __float2bfloat16(pw[idx]);
        wcat[32768 + idx] = __float2bfloat16(gw[idx]);
    } else {                         // outp (128x128) + gl (128x128)
        const int j = idx - 32768;   // < 16384
        wcat2[j] = __float2bfloat16(ow[j]);
        wcat2[16384 + j] = __float2bfloat16(glw[j]);
    }
}

// -------- Kernel A: LN + dual MFMA GEMM (proj & gate) + mask*sigmoid --------
extern "C" __global__ __launch_bounds__(256)
void k_ln_proj(const float* __restrict__ act, const float* __restrict__ mask,
               const float* __restrict__ lnw, const float* __restrict__ lnb,
               const __hip_bfloat16* __restrict__ wcat,
               const float* __restrict__ proj_b, const float* __restrict__ gate_b,
               __hip_bfloat16* __restrict__ lt, __hip_bfloat16* __restrict__ rt,
               __hip_bfloat16* __restrict__ xh)
{
    __shared__ __align__(16) char smem[4 * 64 * 72 * 2];   // 36864 B
    __hip_bfloat16* Xls = (__hip_bfloat16*)smem;            // 16 KB, perm layout
    __hip_bfloat16* tls = (__hip_bfloat16*)smem;            // aliased after barrier
    __shared__ float msk[PB];

    const int t = threadIdx.x;
    const int lane = t & 63, w = t >> 6;
    const int lh = lane & 15, lq = lane >> 4;
    const int P0 = blockIdx.x * PB;

    // ---- LN phase: wave per position, 2 channels/lane ----
#pragma unroll
    for (int it = 0; it < 16; ++it) {
        const int pl = it * 4 + w;
        const int p = P0 + pl;
        const float a0 = act[(size_t)p * TC + lane];
        const float a1 = act[(size_t)p * TC + 64 + lane];
        const float mu = wredsum(a0 + a1) * (1.0f / 128.0f);
        const float d0 = a0 - mu, d1 = a1 - mu;
        const float var = wredsum(d0 * d0 + d1 * d1) * (1.0f / 128.0f);
        const float rs = rsqrtf(var + TEPS);
        const float x0 = d0 * rs * lnw[lane] + lnb[lane];
        const float x1 = d1 * rs * lnw[64 + lane] + lnb[64 + lane];
        const __hip_bfloat16 h0 = __float2bfloat16(x0);
        const __hip_bfloat16 h1 = __float2bfloat16(x1);
        xh[(size_t)p * TC + lane] = h0;
        xh[(size_t)p * TC + 64 + lane] = h1;
        Xls[xidx(pl, lane)] = h0;
        Xls[xidx(pl, lane + 64)] = h1;
    }
    if (t < PB) msk[t] = mask[P0 + t];
    __syncthreads();

    // ---- GEMM: wave w owns proj dims [w*64, w*64+64) + matching gate dims ----
    const int dP = w * 64;
    const int dG = 256 + w * 64;

    f4 acc[4][8];
#pragma unroll
    for (int mi = 0; mi < 4; ++mi)
#pragma unroll
        for (int ni = 0; ni < 8; ++ni)
            acc[mi][ni] = (f4){0.f, 0.f, 0.f, 0.f};

#pragma unroll 1
    for (int kg = 0; kg < 4; ++kg) {
        const int kcol = kg * 32 + lq * 8;
        s8b bfr[8], afr[4];
#pragma unroll
        for (int nd = 0; nd < 4; ++nd) {
            bfr[nd]     = *(const s8b*)&wcat[(size_t)(dP + nd * 16 + lh) * TC + kcol];
            bfr[4 + nd] = *(const s8b*)&wcat[(size_t)(dG + nd * 16 + lh) * TC + kcol];
        }
#pragma unroll
        for (int mi = 0; mi < 4; ++mi)
            afr[mi] = *(const s8b*)&Xls[((mi * 4 + kg) * 64 + lane) * 8];
#pragma unroll
        for (int mi = 0; mi < 4; ++mi)
#pragma unroll
            for (int ni = 0; ni < 8; ++ni)
                acc[mi][ni] = __builtin_amdgcn_mfma_f32_16x16x32_bf16(
                    afr[mi], bfr[ni], acc[mi][ni], 0, 0, 0);
    }

    // ---- epilogue: gate, write to per-wave transpose tile, coalesced global ----
    float pb[4], gb[4];
#pragma unroll
    for (int ni = 0; ni < 4; ++ni) {
        pb[ni] = proj_b[w * 64 + ni * 16 + lh];
        gb[ni] = gate_b[w * 64 + ni * 16 + lh];
    }
    __syncthreads();   // all Xls reads done before tls alias writes
    __hip_bfloat16* mytls = tls + w * (64 * 72);
#pragma unroll
    for (int mi = 0; mi < 4; ++mi)
#pragma unroll
        for (int ni = 0; ni < 4; ++ni) {
            const f4 P = acc[mi][ni];
            const f4 G = acc[mi][ni + 4];
#pragma unroll
            for (int r = 0; r < 4; ++r) {
                const int ploc = mi * 16 + lq * 4 + r;
                const float val = msk[ploc] * (P[r] + pb[ni]) * sigmoidf(G[r] + gb[ni]);
                mytls[(ni * 16 + lh) * 72 + ploc] = __float2bfloat16(val);
            }
        }
    // per-wave private tile: no cross-wave barrier needed
    for (int dl = 0; dl < 64; ++dl) {
        const int d = w * 64 + dl;
        const __hip_bfloat16 v = mytls[dl * 72 + lane];
        if (d < TC) lt[(size_t)d * TNP + P0 + lane] = v;
        else        rt[(size_t)(d - TC) * TNP + P0 + lane] = v;
    }
}

// -------- Kernel B: per-c 512x512x512 NT-GEMM, bf16 MFMA (unchanged) --------
extern "C" __global__ __launch_bounds__(256)
void k_tri_mfma(const __hip_bfloat16* __restrict__ lt,
                const __hip_bfloat16* __restrict__ rt,
                float* __restrict__ tri)
{
    __shared__ __hip_bfloat16 Als[128 * 32];
    __shared__ __hip_bfloat16 Bls[128 * 32];

    const int t = threadIdx.x;
    const int w = t >> 6, lane = t & 63;
    const int i0 = blockIdx.x * 128, j0 = blockIdx.y * 128;
    const int c = blockIdx.z;
    const int wm = w >> 1, wn = w & 1;
    const int lh = lane & 15, lq = lane >> 4;

    const size_t cbase = (size_t)c * TNP;
    const int srow = lane >> 2;
    const int scol = (lane & 3) * 8;

    f4 acc[4][4];
#pragma unroll
    for (int mi = 0; mi < 4; ++mi)
#pragma unroll
        for (int ni = 0; ni < 4; ++ni)
            acc[mi][ni] = (f4){0.f, 0.f, 0.f, 0.f};

    for (int k0 = 0; k0 < TN; k0 += 32) {
        __syncthreads();
#pragma unroll
        for (int s = 0; s < 2; ++s) {
            const int r0 = w * 32 + s * 16;
            const __hip_bfloat16* ga = lt + cbase + (size_t)(i0 + r0 + srow) * TN + k0 + scol;
            const __hip_bfloat16* gb = rt + cbase + (size_t)(j0 + r0 + srow) * TN + k0 + scol;
            __builtin_amdgcn_global_load_lds(
                (const __attribute__((address_space(1))) unsigned*)ga,
                (__attribute__((address_space(3))) unsigned*)&Als[r0 * 32], 16, 0, 0);
            __builtin_amdgcn_global_load_lds(
                (const __attribute__((address_space(1))) unsigned*)gb,
                (__attribute__((address_space(3))) unsigned*)&Bls[r0 * 32], 16, 0, 0);
        }
        __syncthreads();

        s8b af[4], bf[4];
#pragma unroll
        for (int mi = 0; mi < 4; ++mi)
            af[mi] = *(const s8b*)&Als[(wm * 64 + mi * 16 + lh) * 32 + lq * 8];
#pragma unroll
        for (int ni = 0; ni < 4; ++ni)
            bf[ni] = *(const s8b*)&Bls[(wn * 64 + ni * 16 + lh) * 32 + lq * 8];
#pragma unroll
        for (int mi = 0; mi < 4; ++mi)
#pragma unroll
            for (int ni = 0; ni < 4; ++ni)
                acc[mi][ni] = __builtin_amdgcn_mfma_f32_16x16x32_bf16(
                    af[mi], bf[ni], acc[mi][ni], 0, 0, 0);
    }

    float* outp = tri + cbase;
#pragma unroll
    for (int mi = 0; mi < 4; ++mi) {
#pragma unroll
        for (int ni = 0; ni < 4; ++ni) {
            const f4 v = acc[mi][ni];
            const int ib = i0 + wm * 64 + mi * 16 + lq * 4;
            const int jb = j0 + wn * 64 + ni * 16 + lh;
#pragma unroll
            for (int r = 0; r < 4; ++r)
                outp[(size_t)(ib + r) * TN + jb] = v[r];
        }
    }
}

// -------- Kernel C: LN(tri) + MFMA out-proj + gl-gate, direct store --------
extern "C" __global__ __launch_bounds__(256)
void k_out_proj(const float* __restrict__ tri, const __hip_bfloat16* __restrict__ xh,
                const float* __restrict__ cnw, const float* __restrict__ cnb,
                const __hip_bfloat16* __restrict__ wcat2,
                const float* __restrict__ outp_b, const float* __restrict__ gl_b,
                float* __restrict__ outb)
{
    __shared__ float ys[PB * 129];                  // 33 KB staging/LN
    __shared__ __align__(16) __hip_bfloat16 Yls[PB * TC];   // 16 KB perm
    __shared__ __align__(16) __hip_bfloat16 Hls[PB * TC];   // 16 KB perm

    const int t = threadIdx.x;
    const int lane = t & 63, w = t >> 6;
    const int lh = lane & 15, lq = lane >> 4;
    const int P0 = blockIdx.x * PB;

    // stage tri [c][p] -> ys[p][c] (256 B coalesced reads along p)
    {
        const int pl = t & 63;
        const int ch0 = t >> 6;   // 0..3
#pragma unroll
        for (int cc = 0; cc < 32; ++cc) {
            const int ch = cc * 4 + ch0;
            ys[pl * 129 + ch] = tri[(size_t)ch * TNP + P0 + pl];
        }
    }
    __syncthreads();

    // LN + stage gate input, both into perm layout
#pragma unroll
    for (int it = 0; it < 16; ++it) {
        const int pl = it * 4 + w;
        const int p = P0 + pl;
        const float a0 = ys[pl * 129 + lane];
        const float a1 = ys[pl * 129 + 64 + lane];
        const float mu = wredsum(a0 + a1) * (1.0f / 128.0f);
        const float d0 = a0 - mu, d1 = a1 - mu;
        const float var = wredsum(d0 * d0 + d1 * d1) * (1.0f / 128.0f);
        const float rs = rsqrtf(var + TEPS);
        Yls[xidx(pl, lane)]      = __float2bfloat16(d0 * rs * cnw[lane] + cnb[lane]);
        Yls[xidx(pl, lane + 64)] = __float2bfloat16(d1 * rs * cnw[64 + lane] + cnb[64 + lane]);
        Hls[xidx(pl, lane)]      = xh[(size_t)p * TC + lane];
        Hls[xidx(pl, lane + 64)] = xh[(size_t)p * TC + 64 + lane];
    }
    __syncthreads();

    // GEMM: wave w owns outp dims [w*32, w*32+32) + matching gl dims
    const int dO = w * 32;
    const int dG = 128 + w * 32;

    f4 acc[4][4];   // ni 0..1 = outp(Y), 2..3 = gl(H)
#pragma unroll
    for (int mi = 0; mi < 4; ++mi)
#pragma unroll
        for (int ni = 0; ni < 4; ++ni)
            acc[mi][ni] = (f4){0.f, 0.f, 0.f, 0.f};

#pragma unroll 1
    for (int kg = 0; kg < 4; ++kg) {
        const int kcol = kg * 32 + lq * 8;
        s8b bo[2], bg[2], ay[4], ah[4];
#pragma unroll
        for (int nd = 0; nd < 2; ++nd) {
            bo[nd] = *(const s8b*)&wcat2[(size_t)(dO + nd * 16 + lh) * TC + kcol];
            bg[nd] = *(const s8b*)&wcat2[(size_t)(dG + nd * 16 + lh) * TC + kcol];
        }
#pragma unroll
        for (int mi = 0; mi < 4; ++mi) {
            ay[mi] = *(const s8b*)&Yls[((mi * 4 + kg) * 64 + lane) * 8];
            ah[mi] = *(const s8b*)&Hls[((mi * 4 + kg) * 64 + lane) * 8];
        }
#pragma unroll
        for (int mi = 0; mi < 4; ++mi)
#pragma unroll
            for (int nd = 0; nd < 2; ++nd) {
                acc[mi][nd]     = __builtin_amdgcn_mfma_f32_16x16x32_bf16(
                    ay[mi], bo[nd], acc[mi][nd], 0, 0, 0);
                acc[mi][2 + nd] = __builtin_amdgcn_mfma_f32_16x16x32_bf16(
                    ah[mi], bg[nd], acc[mi][2 + nd], 0, 0, 0);
            }
    }

    // epilogue: direct global stores (4x64B segments per instr)
    float ob[2], gb2[2];
#pragma unroll
    for (int nd = 0; nd < 2; ++nd) {
        ob[nd]  = outp_b[w * 32 + nd * 16 + lh];
        gb2[nd] = gl_b[w * 32 + nd * 16 + lh];
    }
#pragma unroll
    for (int mi = 0; mi < 4; ++mi)
#pragma unroll
        for (int nd = 0; nd < 2; ++nd) {
            const f4 O = acc[mi][nd];
            const f4 G = acc[mi][2 + nd];
            const int d = w * 32 + nd * 16 + lh;
#pragma unroll
            for (int r = 0; r < 4; ++r) {
                const int p = P0 + mi * 16 + lq * 4 + r;
                outb[(size_t)p * TC + d] = (O[r] + ob[nd]) * sigmoidf(G[r] + gb2[nd]);
            }
        }
}

extern "C" void kernel_launch(void* const* d_in, const int* in_sizes, int n_in,
                              void* d_out, int out_size, void* d_ws, size_t ws_size,
                              hipStream_t stream)
{
    const float* act    = (const float*)d_in[0];
    const float* mask   = (const float*)d_in[1];
    const float* lnw    = (const float*)d_in[2];
    const float* lnb    = (const float*)d_in[3];
    const float* proj_w = (const float*)d_in[4];
    const float* proj_b = (const float*)d_in[5];
    const float* gate_w = (const float*)d_in[6];
    const float* gate_b = (const float*)d_in[7];
    const float* cnw    = (const float*)d_in[8];
    const float* cnb    = (const float*)d_in[9];
    const float* outp_w = (const float*)d_in[10];
    const float* outp_b = (const float*)d_in[11];
    const float* gl_w   = (const float*)d_in[12];
    const float* gl_b   = (const float*)d_in[13];

    __hip_bfloat16* lt = (__hip_bfloat16*)d_ws;
    __hip_bfloat16* rt = lt + (size_t)TC * TNP;
    __hip_bfloat16* xh = rt + (size_t)TC * TNP;
    float* tri = (float*)(xh + (size_t)TNP * TC);
    __hip_bfloat16* wcat  = (__hip_bfloat16*)(tri + (size_t)TC * TNP);
    __hip_bfloat16* wcat2 = wcat + 512 * TC;
    float* out = (float*)d_out;

    k_wconv<<<192, 256, 0, stream>>>(proj_w, gate_w, outp_w, gl_w, wcat, wcat2);
    k_ln_proj<<<TNP / PB, 256, 0, stream>>>(act, mask, lnw, lnb, wcat,
                                            proj_b, gate_b, lt, rt, xh);
    k_tri_mfma<<<dim3(TN / 128, TN / 128, TC), 256, 0, stream>>>(lt, rt, tri);
    k_out_proj<<<TNP / PB, 256, 0, stream>>>(tri, xh, cnw, cnb, wcat2,
                                             outp_b, gl_b, out);
}

// Round 5
// 359.325 us; speedup vs baseline: 15.0852x; 1.5576x over previous
//
#include <hip/hip_runtime.h>
#include <hip/hip_bf16.h>

// Round 5: split LN from proj-GEMM; swizzled MFMA proj; XCD-swizzled k_tri.
// ws: lt bf16[C][NP] | rt bf16[C][NP] | xh bf16[NP][C] | tri f32[C][NP] | warr | wcat2

constexpr int TN = 512;
constexpr int TC = 128;
constexpr int TNP = TN * TN;
constexpr float TEPS = 1e-5f;

typedef __attribute__((ext_vector_type(8))) short s8b;   // 8 bf16
typedef __attribute__((ext_vector_type(4))) float f4;    // 4 fp32

__device__ __forceinline__ float wredsum(float v) {
#pragma unroll
    for (int off = 32; off > 0; off >>= 1) v += __shfl_xor(v, off);
    return v;
}

__device__ __forceinline__ float sigmoidf(float x) {
    return 1.0f / (1.0f + __expf(-x));
}

__device__ __forceinline__ unsigned short bfbits(float f) {
    __hip_bfloat16 h = __float2bfloat16(f);
    return *reinterpret_cast<unsigned short*>(&h);
}

// -------- weight pre-convert/rearrange --------
// warr[nc][r][k]: r<64 -> proj_w[nc*64+r], r>=64 -> gate_w[nc*64+r-64]  (nc=0..3)
// wcat2: outp_w then gl_w (for kernel C)
extern "C" __global__ __launch_bounds__(256)
void k_wconv(const float* __restrict__ pw, const float* __restrict__ gw,
             const float* __restrict__ ow, const float* __restrict__ glw,
             __hip_bfloat16* __restrict__ warr, __hip_bfloat16* __restrict__ wcat2)
{
    const int idx = blockIdx.x * 256 + threadIdx.x;
    if (idx < 65536) {
        const int nc = idx >> 14;
        const int r = (idx >> 7) & 127;
        const int k = idx & 127;
        const float v = (r < 64) ? pw[(nc * 64 + r) * TC + k]
                                 : gw[(nc * 64 + (r - 64)) * TC + k];
        warr[idx] = __float2bfloat16(v);
    } else if (idx < 98304) {
        const int j = idx - 65536;
        wcat2[j] = __float2bfloat16(j < 16384 ? ow[j] : glw[j - 16384]);
    }
}

// -------- Kernel A1: LayerNorm only (memory-bound, high occupancy) --------
extern "C" __global__ __launch_bounds__(256)
void k_ln(const float* __restrict__ act, const float* __restrict__ lnw,
          const float* __restrict__ lnb, __hip_bfloat16* __restrict__ xh)
{
    const int t = threadIdx.x, lane = t & 63, w = t >> 6;
    const float2 wv = ((const float2*)lnw)[lane];
    const float2 bv = ((const float2*)lnb)[lane];
#pragma unroll 4
    for (int it = 0; it < 32; ++it) {
        const int p = (blockIdx.x * 4 + w) + it * 8192;
        const float2 a = ((const float2*)(act + (size_t)p * TC))[lane];
        const float mu = wredsum(a.x + a.y) * (1.0f / 128.0f);
        const float d0 = a.x - mu, d1 = a.y - mu;
        const float var = wredsum(d0 * d0 + d1 * d1) * (1.0f / 128.0f);
        const float rs = rsqrtf(var + TEPS);
        ushort2 o;
        o.x = bfbits(d0 * rs * wv.x + bv.x);
        o.y = bfbits(d1 * rs * wv.y + bv.y);
        ((ushort2*)(xh + (size_t)p * TC))[lane] = o;
    }
}

// -------- Kernel A2: MFMA proj+gate GEMM with fused mask*sigmoid gating --------
// Tile: 128 positions x (4 chunks of 64 proj + 64 gate dims), K=128.
// Xls/Wls staged via global_load_lds with pre-swizzled source (col16 ^= row&7).
extern "C" __global__ __launch_bounds__(256)
void k_proj(const __hip_bfloat16* __restrict__ xh, const float* __restrict__ mask,
            const __hip_bfloat16* __restrict__ warr,
            const float* __restrict__ proj_b, const float* __restrict__ gate_b,
            __hip_bfloat16* __restrict__ lt, __hip_bfloat16* __restrict__ rt)
{
    __shared__ __align__(16) __hip_bfloat16 Xls[128 * TC];   // 32 KB
    __shared__ __align__(16) __hip_bfloat16 Wls[128 * TC];   // 32 KB, reused as tls
    __shared__ float msk[128];
    __hip_bfloat16* tls = Wls;        // 64 x 134 bf16 = 17 KB, aliased after barrier

    const int t = threadIdx.x, lane = t & 63, w = t >> 6;
    const int lh = lane & 15, lq = lane >> 4;
    const int P0 = blockIdx.x * 128;

    if (t < 128) msk[t] = mask[P0 + t];

    // stage X tile (wave w: rows w*32..w*32+31), swizzled source
    {
        const int rb = w * 32;
#pragma unroll
        for (int s = 0; s < 8; ++s) {
            const int r0 = rb + s * 4;
            const int row = r0 + (lane >> 4);
            const int c16 = (lane & 15) ^ (row & 7);
            const __hip_bfloat16* src = xh + (size_t)(P0 + row) * TC + c16 * 8;
            __builtin_amdgcn_global_load_lds(
                (const __attribute__((address_space(1))) unsigned*)src,
                (__attribute__((address_space(3))) unsigned*)&Xls[r0 * TC], 16, 0, 0);
        }
    }
    __syncthreads();

#pragma unroll 1
    for (int nc = 0; nc < 4; ++nc) {
        // stage W chunk (128 rows: 64 proj + 64 gate), swizzled source
        {
            const __hip_bfloat16* wbase = warr + nc * 16384;
            const int rb = w * 32;
#pragma unroll
            for (int s = 0; s < 8; ++s) {
                const int r0 = rb + s * 4;
                const int row = r0 + (lane >> 4);
                const int c16 = (lane & 15) ^ (row & 7);
                const __hip_bfloat16* src = wbase + (size_t)row * TC + c16 * 8;
                __builtin_amdgcn_global_load_lds(
                    (const __attribute__((address_space(1))) unsigned*)src,
                    (__attribute__((address_space(3))) unsigned*)&Wls[r0 * TC], 16, 0, 0);
            }
        }
        __syncthreads();

        f4 acc[2][8];
#pragma unroll
        for (int mi = 0; mi < 2; ++mi)
#pragma unroll
            for (int ni = 0; ni < 8; ++ni)
                acc[mi][ni] = (f4){0.f, 0.f, 0.f, 0.f};

#pragma unroll
        for (int kg = 0; kg < 4; ++kg) {
            const int kc = ((kg * 4 + lq) ^ (lh & 7)) * 8;
            s8b bfr[8], af[2];
#pragma unroll
            for (int nd = 0; nd < 8; ++nd)
                bfr[nd] = *(const s8b*)&Wls[(nd * 16 + lh) * TC + kc];
#pragma unroll
            for (int mi = 0; mi < 2; ++mi)
                af[mi] = *(const s8b*)&Xls[(w * 32 + mi * 16 + lh) * TC + kc];
#pragma unroll
            for (int mi = 0; mi < 2; ++mi)
#pragma unroll
                for (int nd = 0; nd < 8; ++nd)
                    acc[mi][nd] = __builtin_amdgcn_mfma_f32_16x16x32_bf16(
                        af[mi], bfr[nd], acc[mi][nd], 0, 0, 0);
        }
        __syncthreads();   // Wls frag reads done before tls alias writes

        // epilogue: gate + write transpose tile [64 d][134-pad p]
#pragma unroll
        for (int mi = 0; mi < 2; ++mi)
#pragma unroll
            for (int nd = 0; nd < 4; ++nd) {
                const float pbv = proj_b[nc * 64 + nd * 16 + lh];
                const float gbv = gate_b[nc * 64 + nd * 16 + lh];
                const f4 P = acc[mi][nd];
                const f4 G = acc[mi][4 + nd];
                const int pbase = w * 32 + mi * 16 + lq * 4;
                float v[4];
#pragma unroll
                for (int r = 0; r < 4; ++r)
                    v[r] = msk[pbase + r] * (P[r] + pbv) * sigmoidf(G[r] + gbv);
                ushort2 u01, u23;
                u01.x = bfbits(v[0]); u01.y = bfbits(v[1]);
                u23.x = bfbits(v[2]); u23.y = bfbits(v[3]);
                *(ushort2*)&tls[(nd * 16 + lh) * 134 + pbase]     = u01;
                *(ushort2*)&tls[(nd * 16 + lh) * 134 + pbase + 2] = u23;
            }
        __syncthreads();

        // readout: 64 d-rows, full 128-p rows, ushort2-coalesced (256 B / instr)
        {
            __hip_bfloat16* dst0 = (nc < 2) ? lt + (size_t)(nc * 64) * TNP
                                            : rt + (size_t)((nc - 2) * 64) * TNP;
#pragma unroll
            for (int rr = 0; rr < 16; ++rr) {
                const int dl = w * 16 + rr;
                const ushort2 v = *(const ushort2*)&tls[dl * 134 + lane * 2];
                *(ushort2*)((unsigned short*)(dst0 + (size_t)dl * TNP) + P0 + lane * 2) = v;
            }
        }
        __syncthreads();   // tls reads done before next W staging
    }
}

// -------- Kernel B: per-c 512x512x512 NT-GEMM, bf16 MFMA, XCD-swizzled --------
extern "C" __global__ __launch_bounds__(256)
void k_tri_mfma(const __hip_bfloat16* __restrict__ lt,
                const __hip_bfloat16* __restrict__ rt,
                float* __restrict__ tri)
{
    __shared__ __hip_bfloat16 Als[128 * 32];
    __shared__ __hip_bfloat16 Bls[128 * 32];

    // bijective XCD swizzle: 2048 blocks = 8 XCDs x 256; each XCD owns 16 c-slices.
    const int bid = blockIdx.x;
    const int work = (bid & 7) * 256 + (bid >> 3);
    const int c = work >> 4, tt = work & 15;
    const int i0 = (tt >> 2) * 128, j0 = (tt & 3) * 128;

    const int t = threadIdx.x;
    const int w = t >> 6, lane = t & 63;
    const int wm = w >> 1, wn = w & 1;
    const int lh = lane & 15, lq = lane >> 4;

    const size_t cbase = (size_t)c * TNP;
    const int srow = lane >> 2;
    const int scol = (lane & 3) * 8;

    f4 acc[4][4];
#pragma unroll
    for (int mi = 0; mi < 4; ++mi)
#pragma unroll
        for (int ni = 0; ni < 4; ++ni)
            acc[mi][ni] = (f4){0.f, 0.f, 0.f, 0.f};

    for (int k0 = 0; k0 < TN; k0 += 32) {
        __syncthreads();
#pragma unroll
        for (int s = 0; s < 2; ++s) {
            const int r0 = w * 32 + s * 16;
            const __hip_bfloat16* ga = lt + cbase + (size_t)(i0 + r0 + srow) * TN + k0 + scol;
            const __hip_bfloat16* gb = rt + cbase + (size_t)(j0 + r0 + srow) * TN + k0 + scol;
            __builtin_amdgcn_global_load_lds(
                (const __attribute__((address_space(1))) unsigned*)ga,
                (__attribute__((address_space(3))) unsigned*)&Als[r0 * 32], 16, 0, 0);
            __builtin_amdgcn_global_load_lds(
                (const __attribute__((address_space(1))) unsigned*)gb,
                (__attribute__((address_space(3))) unsigned*)&Bls[r0 * 32], 16, 0, 0);
        }
        __syncthreads();

        s8b af[4], bf[4];
#pragma unroll
        for (int mi = 0; mi < 4; ++mi)
            af[mi] = *(const s8b*)&Als[(wm * 64 + mi * 16 + lh) * 32 + lq * 8];
#pragma unroll
        for (int ni = 0; ni < 4; ++ni)
            bf[ni] = *(const s8b*)&Bls[(wn * 64 + ni * 16 + lh) * 32 + lq * 8];
#pragma unroll
        for (int mi = 0; mi < 4; ++mi)
#pragma unroll
            for (int ni = 0; ni < 4; ++ni)
                acc[mi][ni] = __builtin_amdgcn_mfma_f32_16x16x32_bf16(
                    af[mi], bf[ni], acc[mi][ni], 0, 0, 0);
    }

    float* outp = tri + cbase;
#pragma unroll
    for (int mi = 0; mi < 4; ++mi) {
#pragma unroll
        for (int ni = 0; ni < 4; ++ni) {
            const f4 v = acc[mi][ni];
            const int ib = i0 + wm * 64 + mi * 16 + lq * 4;
            const int jb = j0 + wn * 64 + ni * 16 + lh;
#pragma unroll
            for (int r = 0; r < 4; ++r)
                outp[(size_t)(ib + r) * TN + jb] = v[r];
        }
    }
}

// -------- Kernel C: LN(tri) + MFMA out-proj + gl-gate (unchanged from r4) --------
constexpr int PB = 64;

__device__ __forceinline__ int xidx(int p, int k) {
    return (((p >> 4) * 4 + (k >> 5)) * 64 + (((k >> 3) & 3) * 16 + (p & 15))) * 8 + (k & 7);
}

extern "C" __global__ __launch_bounds__(256)
void k_out_proj(const float* __restrict__ tri, const __hip_bfloat16* __restrict__ xh,
                const float* __restrict__ cnw, const float* __restrict__ cnb,
                const __hip_bfloat16* __restrict__ wcat2,
                const float* __restrict__ outp_b, const float* __restrict__ gl_b,
                float* __restrict__ outb)
{
    __shared__ float ys[PB * 129];
    __shared__ __align__(16) __hip_bfloat16 Yls[PB * TC];
    __shared__ __align__(16) __hip_bfloat16 Hls[PB * TC];

    const int t = threadIdx.x;
    const int lane = t & 63, w = t >> 6;
    const int lh = lane & 15, lq = lane >> 4;
    const int P0 = blockIdx.x * PB;

    {
        const int pl = t & 63;
        const int ch0 = t >> 6;
#pragma unroll
        for (int cc = 0; cc < 32; ++cc) {
            const int ch = cc * 4 + ch0;
            ys[pl * 129 + ch] = tri[(size_t)ch * TNP + P0 + pl];
        }
    }
    __syncthreads();

#pragma unroll
    for (int it = 0; it < 16; ++it) {
        const int pl = it * 4 + w;
        const int p = P0 + pl;
        const float a0 = ys[pl * 129 + lane];
        const float a1 = ys[pl * 129 + 64 + lane];
        const float mu = wredsum(a0 + a1) * (1.0f / 128.0f);
        const float d0 = a0 - mu, d1 = a1 - mu;
        const float var = wredsum(d0 * d0 + d1 * d1) * (1.0f / 128.0f);
        const float rs = rsqrtf(var + TEPS);
        Yls[xidx(pl, lane)]      = __float2bfloat16(d0 * rs * cnw[lane] + cnb[lane]);
        Yls[xidx(pl, lane + 64)] = __float2bfloat16(d1 * rs * cnw[64 + lane] + cnb[64 + lane]);
        Hls[xidx(pl, lane)]      = xh[(size_t)p * TC + lane];
        Hls[xidx(pl, lane + 64)] = xh[(size_t)p * TC + 64 + lane];
    }
    __syncthreads();

    const int dO = w * 32;
    const int dG = 128 + w * 32;

    f4 acc[4][4];
#pragma unroll
    for (int mi = 0; mi < 4; ++mi)
#pragma unroll
        for (int ni = 0; ni < 4; ++ni)
            acc[mi][ni] = (f4){0.f, 0.f, 0.f, 0.f};

#pragma unroll 1
    for (int kg = 0; kg < 4; ++kg) {
        const int kcol = kg * 32 + lq * 8;
        s8b bo[2], bg[2], ay[4], ah[4];
#pragma unroll
        for (int nd = 0; nd < 2; ++nd) {
            bo[nd] = *(const s8b*)&wcat2[(size_t)(dO + nd * 16 + lh) * TC + kcol];
            bg[nd] = *(const s8b*)&wcat2[(size_t)(dG + nd * 16 + lh) * TC + kcol];
        }
#pragma unroll
        for (int mi = 0; mi < 4; ++mi) {
            ay[mi] = *(const s8b*)&Yls[((mi * 4 + kg) * 64 + lane) * 8];
            ah[mi] = *(const s8b*)&Hls[((mi * 4 + kg) * 64 + lane) * 8];
        }
#pragma unroll
        for (int mi = 0; mi < 4; ++mi)
#pragma unroll
            for (int nd = 0; nd < 2; ++nd) {
                acc[mi][nd]     = __builtin_amdgcn_mfma_f32_16x16x32_bf16(
                    ay[mi], bo[nd], acc[mi][nd], 0, 0, 0);
                acc[mi][2 + nd] = __builtin_amdgcn_mfma_f32_16x16x32_bf16(
                    ah[mi], bg[nd], acc[mi][2 + nd], 0, 0, 0);
            }
    }

    float ob[2], gb2[2];
#pragma unroll
    for (int nd = 0; nd < 2; ++nd) {
        ob[nd]  = outp_b[w * 32 + nd * 16 + lh];
        gb2[nd] = gl_b[w * 32 + nd * 16 + lh];
    }
#pragma unroll
    for (int mi = 0; mi < 4; ++mi)
#pragma unroll
        for (int nd = 0; nd < 2; ++nd) {
            const f4 O = acc[mi][nd];
            const f4 G = acc[mi][2 + nd];
            const int d = w * 32 + nd * 16 + lh;
#pragma unroll
            for (int r = 0; r < 4; ++r) {
                const int p = P0 + mi * 16 + lq * 4 + r;
                outb[(size_t)p * TC + d] = (O[r] + ob[nd]) * sigmoidf(G[r] + gb2[nd]);
            }
        }
}

extern "C" void kernel_launch(void* const* d_in, const int* in_sizes, int n_in,
                              void* d_out, int out_size, void* d_ws, size_t ws_size,
                              hipStream_t stream)
{
    const float* act    = (const float*)d_in[0];
    const float* mask   = (const float*)d_in[1];
    const float* lnw    = (const float*)d_in[2];
    const float* lnb    = (const float*)d_in[3];
    const float* proj_w = (const float*)d_in[4];
    const float* proj_b = (const float*)d_in[5];
    const float* gate_w = (const float*)d_in[6];
    const float* gate_b = (const float*)d_in[7];
    const float* cnw    = (const float*)d_in[8];
    const float* cnb    = (const float*)d_in[9];
    const float* outp_w = (const float*)d_in[10];
    const float* outp_b = (const float*)d_in[11];
    const float* gl_w   = (const float*)d_in[12];
    const float* gl_b   = (const float*)d_in[13];

    __hip_bfloat16* lt = (__hip_bfloat16*)d_ws;
    __hip_bfloat16* rt = lt + (size_t)TC * TNP;
    __hip_bfloat16* xh = rt + (size_t)TC * TNP;
    float* tri = (float*)(xh + (size_t)TNP * TC);
    __hip_bfloat16* warr  = (__hip_bfloat16*)(tri + (size_t)TC * TNP);
    __hip_bfloat16* wcat2 = warr + 4 * 128 * TC;
    float* out = (float*)d_out;

    k_wconv<<<384, 256, 0, stream>>>(proj_w, gate_w, outp_w, gl_w, warr, wcat2);
    k_ln<<<2048, 256, 0, stream>>>(act, lnw, lnb, xh);
    k_proj<<<TNP / 128, 256, 0, stream>>>(xh, mask, warr, proj_b, gate_b, lt, rt);
    k_tri_mfma<<<2048, 256, 0, stream>>>(lt, rt, tri);
    k_out_proj<<<TNP / PB, 256, 0, stream>>>(tri, xh, cnw, cnb, wcat2,
                                             outp_b, gl_b, out);
}

// Round 6
// 351.275 us; speedup vs baseline: 15.4309x; 1.0229x over previous
//
#include <hip/hip_runtime.h>
#include <hip/hip_bf16.h>

// Round 6: global frag-layout xh_perm; register-direct W/X frags; bf16 trih;
// swizzled Y-perm in kernel C.
// ws: lt[C][NP] | rt[C][NP] | xhp (perm) | trih[C][NP] (all bf16, 64MB each) | warr | wcat2

constexpr int TN = 512;
constexpr int TC = 128;
constexpr int TNP = TN * TN;
constexpr float TEPS = 1e-5f;

typedef __attribute__((ext_vector_type(8))) short s8b;   // 8 bf16
typedef __attribute__((ext_vector_type(4))) float f4;    // 4 fp32

__device__ __forceinline__ float wredsum(float v) {
#pragma unroll
    for (int off = 32; off > 0; off >>= 1) v += __shfl_xor(v, off);
    return v;
}
__device__ __forceinline__ float sigmoidf(float x) { return 1.0f / (1.0f + __expf(-x)); }
__device__ __forceinline__ unsigned short bfbits(float f) {
    __hip_bfloat16 h = __float2bfloat16(f);
    return *reinterpret_cast<unsigned short*>(&h);
}
__device__ __forceinline__ float bf2f(unsigned short u) {
    return __uint_as_float(((unsigned int)u) << 16);
}

// xh_perm layout: group g = p>>4, unit kg = c>>5, slot = lq*16 + lh (lq=(c>>3)&3,
// lh=p&15), elem j = c&7.  elem offset = g*2048 + kg*512 + slot*8 + j.

// -------- weight pre-convert/rearrange --------
extern "C" __global__ __launch_bounds__(256)
void k_wconv(const float* __restrict__ pw, const float* __restrict__ gw,
             const float* __restrict__ ow, const float* __restrict__ glw,
             __hip_bfloat16* __restrict__ warr, __hip_bfloat16* __restrict__ wcat2)
{
    const int idx = blockIdx.x * 256 + threadIdx.x;
    if (idx < 65536) {
        const int nc = idx >> 14;
        const int r = (idx >> 7) & 127;
        const int k = idx & 127;
        const float v = (r < 64) ? pw[(nc * 64 + r) * TC + k]
                                 : gw[(nc * 64 + (r - 64)) * TC + k];
        warr[idx] = __float2bfloat16(v);
    } else if (idx < 98304) {
        const int j = idx - 65536;
        wcat2[j] = __float2bfloat16(j < 16384 ? ow[j] : glw[j - 16384]);
    }
}

// -------- Kernel A1: LayerNorm -> xh_perm (frag layout, coalesced 16B stores) ----
extern "C" __global__ __launch_bounds__(256)
void k_ln(const float* __restrict__ act, const float* __restrict__ lnw,
          const float* __restrict__ lnb, __hip_bfloat16* __restrict__ xhp)
{
    __shared__ __align__(16) unsigned short t16[16 * 136];
    const int t = threadIdx.x, lane = t & 63, w = t >> 6;
    const int P0 = blockIdx.x * 64;
    const float2 wv = ((const float2*)lnw)[lane];
    const float2 bv = ((const float2*)lnb)[lane];
    unsigned short* xb = (unsigned short*)xhp;

    for (int r = 0; r < 4; ++r) {
#pragma unroll
        for (int q = 0; q < 4; ++q) {
            const int prow = w * 4 + q;                 // p & 15
            const int p = P0 + r * 16 + prow;
            const float2 a = ((const float2*)(act + (size_t)p * TC))[lane];
            const float mu = wredsum(a.x + a.y) * (1.0f / 128.0f);
            const float d0 = a.x - mu, d1 = a.y - mu;
            const float var = wredsum(d0 * d0 + d1 * d1) * (1.0f / 128.0f);
            const float rs = rsqrtf(var + TEPS);
            ushort2 o;
            o.x = bfbits(d0 * rs * wv.x + bv.x);
            o.y = bfbits(d1 * rs * wv.y + bv.y);
            *(ushort2*)&t16[prow * 136 + lane * 2] = o;
        }
        __syncthreads();
        {   // thread t -> 16B chunk slot t of this 16-position group
            const int kg = t >> 6, lq = (t >> 4) & 3, lh = t & 15;
            const s8b v = *(const s8b*)&t16[lh * 136 + kg * 32 + lq * 8];
            *(s8b*)(xb + (size_t)((P0 >> 4) + r) * 2048 + (size_t)t * 8) = v;
        }
        __syncthreads();
    }
}

// -------- Kernel A2: MFMA proj+gate GEMM, frags from global, fused gating -------
extern "C" __global__ __launch_bounds__(256)
void k_proj(const __hip_bfloat16* __restrict__ xhp, const float* __restrict__ mask,
            const __hip_bfloat16* __restrict__ warr,
            const float* __restrict__ proj_b, const float* __restrict__ gate_b,
            __hip_bfloat16* __restrict__ lt, __hip_bfloat16* __restrict__ rt)
{
    __shared__ __align__(4) unsigned short tls[64 * 134];   // transpose tile
    __shared__ float msk[128];

    const int t = threadIdx.x, lane = t & 63, w = t >> 6;
    const int lh = lane & 15, lq = lane >> 4;
    const int P0 = blockIdx.x * 128;
    const unsigned short* xb = (const unsigned short*)xhp;
    const unsigned short* wb0 = (const unsigned short*)warr;

    if (t < 128) msk[t] = mask[P0 + t];

    // X-frags straight to registers (held across all nc chunks)
    s8b af[2][4];
#pragma unroll
    for (int mi = 0; mi < 2; ++mi)
#pragma unroll
        for (int kg = 0; kg < 4; ++kg) {
            const size_t g = (size_t)(P0 >> 4) + w * 2 + mi;
            af[mi][kg] = *(const s8b*)(xb + g * 2048 + kg * 512 + (size_t)lane * 8);
        }
    __syncthreads();

#pragma unroll 1
    for (int nc = 0; nc < 4; ++nc) {
        const unsigned short* wb = wb0 + nc * 16384;
        f4 acc[2][8];
#pragma unroll
        for (int mi = 0; mi < 2; ++mi)
#pragma unroll
            for (int ni = 0; ni < 8; ++ni)
                acc[mi][ni] = (f4){0.f, 0.f, 0.f, 0.f};

#pragma unroll
        for (int kg = 0; kg < 4; ++kg) {
            s8b bfr[8];
#pragma unroll
            for (int nd = 0; nd < 8; ++nd)
                bfr[nd] = *(const s8b*)(wb + (nd * 16 + lh) * TC + kg * 32 + lq * 8);
#pragma unroll
            for (int mi = 0; mi < 2; ++mi)
#pragma unroll
                for (int nd = 0; nd < 8; ++nd)
                    acc[mi][nd] = __builtin_amdgcn_mfma_f32_16x16x32_bf16(
                        af[mi][kg], bfr[nd], acc[mi][nd], 0, 0, 0);
        }

        // epilogue: gate + transpose tile [64 d][134 p]
#pragma unroll
        for (int mi = 0; mi < 2; ++mi)
#pragma unroll
            for (int nd = 0; nd < 4; ++nd) {
                const float pbv = proj_b[nc * 64 + nd * 16 + lh];
                const float gbv = gate_b[nc * 64 + nd * 16 + lh];
                const f4 P = acc[mi][nd];
                const f4 G = acc[mi][4 + nd];
                const int pbase = w * 32 + mi * 16 + lq * 4;
                float v[4];
#pragma unroll
                for (int r = 0; r < 4; ++r)
                    v[r] = msk[pbase + r] * (P[r] + pbv) * sigmoidf(G[r] + gbv);
                ushort2 u01, u23;
                u01.x = bfbits(v[0]); u01.y = bfbits(v[1]);
                u23.x = bfbits(v[2]); u23.y = bfbits(v[3]);
                *(ushort2*)&tls[(nd * 16 + lh) * 134 + pbase]     = u01;
                *(ushort2*)&tls[(nd * 16 + lh) * 134 + pbase + 2] = u23;
            }
        __syncthreads();
        {   // readout: 64 d-rows x 128 p, ushort2-coalesced
            __hip_bfloat16* dst0 = (nc < 2) ? lt + (size_t)(nc * 64) * TNP
                                            : rt + (size_t)((nc - 2) * 64) * TNP;
#pragma unroll
            for (int rr = 0; rr < 16; ++rr) {
                const int dl = w * 16 + rr;
                const ushort2 v = *(const ushort2*)&tls[dl * 134 + lane * 2];
                *(ushort2*)((unsigned short*)(dst0 + (size_t)dl * TNP) + P0 + lane * 2) = v;
            }
        }
        __syncthreads();
    }
}

// -------- Kernel B: per-c NT-GEMM, bf16 in/out, XCD-swizzled, LDS-transposed C --
extern "C" __global__ __launch_bounds__(256)
void k_tri_mfma(const __hip_bfloat16* __restrict__ lt,
                const __hip_bfloat16* __restrict__ rt,
                __hip_bfloat16* __restrict__ trih)
{
    __shared__ __align__(16) char smem[128 * 136 * 2];   // 34816 B
    __hip_bfloat16* Als = (__hip_bfloat16*)smem;          // 8 KB
    __hip_bfloat16* Bls = (__hip_bfloat16*)(smem + 8192); // 8 KB
    unsigned short* Cls = (unsigned short*)smem;          // aliased after K loop

    const int bid = blockIdx.x;
    const int work = (bid & 7) * 256 + (bid >> 3);
    const int c = work >> 4, tt = work & 15;
    const int i0 = (tt >> 2) * 128, j0 = (tt & 3) * 128;

    const int t = threadIdx.x;
    const int w = t >> 6, lane = t & 63;
    const int wm = w >> 1, wn = w & 1;
    const int lh = lane & 15, lq = lane >> 4;

    const size_t cbase = (size_t)c * TNP;
    const int srow = lane >> 2;
    const int scol = (lane & 3) * 8;

    f4 acc[4][4];
#pragma unroll
    for (int mi = 0; mi < 4; ++mi)
#pragma unroll
        for (int ni = 0; ni < 4; ++ni)
            acc[mi][ni] = (f4){0.f, 0.f, 0.f, 0.f};

    for (int k0 = 0; k0 < TN; k0 += 32) {
        __syncthreads();
#pragma unroll
        for (int s = 0; s < 2; ++s) {
            const int r0 = w * 32 + s * 16;
            const __hip_bfloat16* ga = lt + cbase + (size_t)(i0 + r0 + srow) * TN + k0 + scol;
            const __hip_bfloat16* gb = rt + cbase + (size_t)(j0 + r0 + srow) * TN + k0 + scol;
            __builtin_amdgcn_global_load_lds(
                (const __attribute__((address_space(1))) unsigned*)ga,
                (__attribute__((address_space(3))) unsigned*)&Als[r0 * 32], 16, 0, 0);
            __builtin_amdgcn_global_load_lds(
                (const __attribute__((address_space(1))) unsigned*)gb,
                (__attribute__((address_space(3))) unsigned*)&Bls[r0 * 32], 16, 0, 0);
        }
        __syncthreads();

        s8b afr[4], bfr[4];
#pragma unroll
        for (int mi = 0; mi < 4; ++mi)
            afr[mi] = *(const s8b*)&Als[(wm * 64 + mi * 16 + lh) * 32 + lq * 8];
#pragma unroll
        for (int ni = 0; ni < 4; ++ni)
            bfr[ni] = *(const s8b*)&Bls[(wn * 64 + ni * 16 + lh) * 32 + lq * 8];
#pragma unroll
        for (int mi = 0; mi < 4; ++mi)
#pragma unroll
            for (int ni = 0; ni < 4; ++ni)
                acc[mi][ni] = __builtin_amdgcn_mfma_f32_16x16x32_bf16(
                    afr[mi], bfr[ni], acc[mi][ni], 0, 0, 0);
    }

    __syncthreads();   // frag reads done before Cls alias writes
#pragma unroll
    for (int mi = 0; mi < 4; ++mi)
#pragma unroll
        for (int ni = 0; ni < 4; ++ni) {
            const f4 v = acc[mi][ni];
            const int jl = wn * 64 + ni * 16 + lh;
#pragma unroll
            for (int r = 0; r < 4; ++r) {
                const int il = wm * 64 + mi * 16 + lq * 4 + r;
                Cls[il * 136 + jl] = bfbits(v[r]);
            }
        }
    __syncthreads();
    {
        unsigned short* ob = (unsigned short*)trih + cbase;
#pragma unroll
        for (int qq = 0; qq < 8; ++qq) {
            const int row = qq * 16 + (t >> 4);
            const int c16 = t & 15;
            const s8b v = *(const s8b*)&Cls[row * 136 + c16 * 8];
            *(s8b*)&ob[(size_t)(i0 + row) * TN + j0 + c16 * 8] = v;
        }
    }
}

// -------- Kernel C: LN(trih) + MFMA out-proj + gl-gate --------
constexpr int PB = 64;

extern "C" __global__ __launch_bounds__(256)
void k_out_proj(const __hip_bfloat16* __restrict__ trih,
                const __hip_bfloat16* __restrict__ xhp,
                const float* __restrict__ cnw, const float* __restrict__ cnb,
                const __hip_bfloat16* __restrict__ wcat2,
                const float* __restrict__ outp_b, const float* __restrict__ gl_b,
                float* __restrict__ outb)
{
    __shared__ unsigned short ysb[PB * 134];                 // [p][c] staging
    __shared__ __align__(16) unsigned short Yls[PB * TC];    // perm + XOR swizzle

    const int t = threadIdx.x, lane = t & 63, w = t >> 6;
    const int lh = lane & 15, lq = lane >> 4;
    const int P0 = blockIdx.x * PB;
    const unsigned short* tb = (const unsigned short*)trih;
    const unsigned short* xb = (const unsigned short*)xhp;
    const unsigned short* wb = (const unsigned short*)wcat2;

    // stage trih [c][p-tile] -> ysb[p][c]
    {
        const int c0 = t >> 5, pp = (t & 31) * 2;
#pragma unroll
        for (int cc = 0; cc < 16; ++cc) {
            const int ch = cc * 8 + c0;
            const ushort2 v = *(const ushort2*)(tb + (size_t)ch * TNP + P0 + pp);
            ysb[pp * 134 + ch] = v.x;
            ysb[(pp + 1) * 134 + ch] = v.y;
        }
    }
    __syncthreads();

    // LN: wave per position; write Y-perm with XOR-swizzled chunk index
    {
        const float2 wv = ((const float2*)cnw)[lane];
        const float2 bv = ((const float2*)cnb)[lane];
        const int sw = (lane >> 2) & 7;          // write-side swizzle key
#pragma unroll 2
        for (int it = 0; it < 16; ++it) {
            const int pl = it * 4 + w;
            const ushort2 uv = *(const ushort2*)&ysb[pl * 134 + lane * 2];
            const float a0 = bf2f(uv.x), a1 = bf2f(uv.y);
            const float mu = wredsum(a0 + a1) * (1.0f / 128.0f);
            const float d0 = a0 - mu, d1 = a1 - mu;
            const float var = wredsum(d0 * d0 + d1 * d1) * (1.0f / 128.0f);
            const float rs = rsqrtf(var + TEPS);
            ushort2 o;
            o.x = bfbits(d0 * rs * wv.x + bv.x);
            o.y = bfbits(d1 * rs * wv.y + bv.y);
            const int chunk = ((pl >> 4) * 4 + (lane >> 4)) * 64
                            + ((lane >> 2) & 3) * 16 + ((pl & 15) ^ sw);
            *(ushort2*)&Yls[chunk * 8 + (lane & 3) * 2] = o;
        }
    }
    __syncthreads();

    // GEMM: wave w owns outp dims [w*32,+32) and matching gl dims
    const int dO = w * 32;
    const int dG = 128 + w * 32;

    f4 acc[4][4];   // ni 0..1 = outp(Y), 2..3 = gl(H)
#pragma unroll
    for (int mi = 0; mi < 4; ++mi)
#pragma unroll
        for (int ni = 0; ni < 4; ++ni)
            acc[mi][ni] = (f4){0.f, 0.f, 0.f, 0.f};

#pragma unroll
    for (int kg = 0; kg < 4; ++kg) {
        s8b bo[2], bg[2], ay[4], ah[4];
#pragma unroll
        for (int nd = 0; nd < 2; ++nd) {
            bo[nd] = *(const s8b*)(wb + (dO + nd * 16 + lh) * TC + kg * 32 + lq * 8);
            bg[nd] = *(const s8b*)(wb + (dG + nd * 16 + lh) * TC + kg * 32 + lq * 8);
        }
        const int rsw = (kg * 4 + lq) & 7;       // read-side swizzle key
#pragma unroll
        for (int mi = 0; mi < 4; ++mi) {
            const int chunk = (mi * 4 + kg) * 64 + lq * 16 + (lh ^ rsw);
            ay[mi] = *(const s8b*)&Yls[chunk * 8];
            ah[mi] = *(const s8b*)(xb + (size_t)((P0 >> 4) + mi) * 2048
                                      + kg * 512 + (size_t)lane * 8);
        }
#pragma unroll
        for (int mi = 0; mi < 4; ++mi)
#pragma unroll
            for (int nd = 0; nd < 2; ++nd) {
                acc[mi][nd]     = __builtin_amdgcn_mfma_f32_16x16x32_bf16(
                    ay[mi], bo[nd], acc[mi][nd], 0, 0, 0);
                acc[mi][2 + nd] = __builtin_amdgcn_mfma_f32_16x16x32_bf16(
                    ah[mi], bg[nd], acc[mi][2 + nd], 0, 0, 0);
            }
    }

    float ob[2], gb2[2];
#pragma unroll
    for (int nd = 0; nd < 2; ++nd) {
        ob[nd]  = outp_b[w * 32 + nd * 16 + lh];
        gb2[nd] = gl_b[w * 32 + nd * 16 + lh];
    }
#pragma unroll
    for (int mi = 0; mi < 4; ++mi)
#pragma unroll
        for (int nd = 0; nd < 2; ++nd) {
            const f4 O = acc[mi][nd];
            const f4 G = acc[mi][2 + nd];
            const int d = w * 32 + nd * 16 + lh;
#pragma unroll
            for (int r = 0; r < 4; ++r) {
                const int p = P0 + mi * 16 + lq * 4 + r;
                outb[(size_t)p * TC + d] = (O[r] + ob[nd]) * sigmoidf(G[r] + gb2[nd]);
            }
        }
}

extern "C" void kernel_launch(void* const* d_in, const int* in_sizes, int n_in,
                              void* d_out, int out_size, void* d_ws, size_t ws_size,
                              hipStream_t stream)
{
    const float* act    = (const float*)d_in[0];
    const float* mask   = (const float*)d_in[1];
    const float* lnw    = (const float*)d_in[2];
    const float* lnb    = (const float*)d_in[3];
    const float* proj_w = (const float*)d_in[4];
    const float* proj_b = (const float*)d_in[5];
    const float* gate_w = (const float*)d_in[6];
    const float* gate_b = (const float*)d_in[7];
    const float* cnw    = (const float*)d_in[8];
    const float* cnb    = (const float*)d_in[9];
    const float* outp_w = (const float*)d_in[10];
    const float* outp_b = (const float*)d_in[11];
    const float* gl_w   = (const float*)d_in[12];
    const float* gl_b   = (const float*)d_in[13];

    __hip_bfloat16* lt   = (__hip_bfloat16*)d_ws;
    __hip_bfloat16* rt   = lt + (size_t)TC * TNP;
    __hip_bfloat16* xhp  = rt + (size_t)TC * TNP;
    __hip_bfloat16* trih = xhp + (size_t)TNP * TC;
    __hip_bfloat16* warr = trih + (size_t)TC * TNP;
    __hip_bfloat16* wcat2 = warr + 4 * 128 * TC;
    float* out = (float*)d_out;

    k_wconv<<<384, 256, 0, stream>>>(proj_w, gate_w, outp_w, gl_w, warr, wcat2);
    k_ln<<<TNP / 64, 256, 0, stream>>>(act, lnw, lnb, xhp);
    k_proj<<<TNP / 128, 256, 0, stream>>>(xhp, mask, warr, proj_b, gate_b, lt, rt);
    k_tri_mfma<<<2048, 256, 0, stream>>>(lt, rt, trih);
    k_out_proj<<<TNP / PB, 256, 0, stream>>>(trih, xhp, cnw, cnb, wcat2,
                                             outp_b, gl_b, out);
}

// Round 7
// 298.267 us; speedup vs baseline: 18.1733x; 1.1777x over previous
//
#include <hip/hip_runtime.h>
#include <hip/hip_bf16.h>

// Round 7: k_proj rebuilt — one-shot tiles, nc loop -> grid, frag-unit LDS,
// linear global_load_lds staging for X and W. Others unchanged from r6.
// ws: lt[C][NP] | rt[C][NP] | xhp (frag) | trih[C][NP] (bf16, 64MB each) | warr | wcat2

constexpr int TN = 512;
constexpr int TC = 128;
constexpr int TNP = TN * TN;
constexpr float TEPS = 1e-5f;

typedef __attribute__((ext_vector_type(8))) short s8b;   // 8 bf16
typedef __attribute__((ext_vector_type(4))) float f4;    // 4 fp32

__device__ __forceinline__ float wredsum(float v) {
#pragma unroll
    for (int off = 32; off > 0; off >>= 1) v += __shfl_xor(v, off);
    return v;
}
__device__ __forceinline__ float sigmoidf(float x) { return 1.0f / (1.0f + __expf(-x)); }
__device__ __forceinline__ unsigned short bfbits(float f) {
    __hip_bfloat16 h = __float2bfloat16(f);
    return *reinterpret_cast<unsigned short*>(&h);
}
__device__ __forceinline__ float bf2f(unsigned short u) {
    return __uint_as_float(((unsigned int)u) << 16);
}

// xh_perm layout: unit(g = p>>4, kg = c>>5) of 512 ushorts; within unit:
// slot = lq*16 + lh (lq=(c>>3)&3, lh=p&15), elem j = c&7.
// warr frag layout: unit(nc, rg = row>>4, kg) — row = rg*16+lh, k = kg*32+lq*8+j;
// rows 0..63 of chunk nc = proj dims nc*64.., rows 64..127 = gate dims nc*64..

// -------- weight pre-convert/rearrange --------
extern "C" __global__ __launch_bounds__(256)
void k_wconv(const float* __restrict__ pw, const float* __restrict__ gw,
             const float* __restrict__ ow, const float* __restrict__ glw,
             __hip_bfloat16* __restrict__ warr, __hip_bfloat16* __restrict__ wcat2)
{
    const int idx = blockIdx.x * 256 + threadIdx.x;
    if (idx < 65536) {
        const int j = idx & 7;
        const int slot = (idx >> 3) & 63;
        const int kg = (idx >> 9) & 3;
        const int rg = (idx >> 11) & 7;
        const int nc = idx >> 14;
        const int lh = slot & 15, lq = slot >> 4;
        const int row = rg * 16 + lh;
        const int k = kg * 32 + lq * 8 + j;
        const float v = (row < 64) ? pw[(nc * 64 + row) * TC + k]
                                   : gw[(nc * 64 + (row - 64)) * TC + k];
        warr[idx] = __float2bfloat16(v);
    } else if (idx < 98304) {
        const int j = idx - 65536;
        wcat2[j] = __float2bfloat16(j < 16384 ? ow[j] : glw[j - 16384]);
    }
}

// -------- Kernel A1: LayerNorm -> xh_perm (frag layout, coalesced 16B stores) ----
extern "C" __global__ __launch_bounds__(256)
void k_ln(const float* __restrict__ act, const float* __restrict__ lnw,
          const float* __restrict__ lnb, __hip_bfloat16* __restrict__ xhp)
{
    __shared__ __align__(16) unsigned short t16[16 * 136];
    const int t = threadIdx.x, lane = t & 63, w = t >> 6;
    const int P0 = blockIdx.x * 64;
    const float2 wv = ((const float2*)lnw)[lane];
    const float2 bv = ((const float2*)lnb)[lane];
    unsigned short* xb = (unsigned short*)xhp;

    for (int r = 0; r < 4; ++r) {
#pragma unroll
        for (int q = 0; q < 4; ++q) {
            const int prow = w * 4 + q;
            const int p = P0 + r * 16 + prow;
            const float2 a = ((const float2*)(act + (size_t)p * TC))[lane];
            const float mu = wredsum(a.x + a.y) * (1.0f / 128.0f);
            const float d0 = a.x - mu, d1 = a.y - mu;
            const float var = wredsum(d0 * d0 + d1 * d1) * (1.0f / 128.0f);
            const float rs = rsqrtf(var + TEPS);
            ushort2 o;
            o.x = bfbits(d0 * rs * wv.x + bv.x);
            o.y = bfbits(d1 * rs * wv.y + bv.y);
            *(ushort2*)&t16[prow * 136 + lane * 2] = o;
        }
        __syncthreads();
        {
            const int kg = t >> 6, lq = (t >> 4) & 3, lh = t & 15;
            const s8b v = *(const s8b*)&t16[lh * 136 + kg * 32 + lq * 8];
            *(s8b*)(xb + (size_t)((P0 >> 4) + r) * 2048 + (size_t)t * 8) = v;
        }
        __syncthreads();
    }
}

// -------- Kernel A2: MFMA proj+gate GEMM, one-shot tile, fused gating ----------
// Block: 128 positions x 64 proj dims (+64 matching gate dims). Grid 8192.
extern "C" __global__ __launch_bounds__(256)
void k_proj(const __hip_bfloat16* __restrict__ xhp, const float* __restrict__ mask,
            const __hip_bfloat16* __restrict__ warr,
            const float* __restrict__ proj_b, const float* __restrict__ gate_b,
            __hip_bfloat16* __restrict__ lt, __hip_bfloat16* __restrict__ rt)
{
    __shared__ __align__(16) unsigned short Xls[128 * TC];   // 32 KB, frag units
    __shared__ __align__(16) unsigned short Wls[128 * TC];   // 32 KB, frag units
    __shared__ float msk[128];
    unsigned short* tls = Xls;   // 64x134 transpose tile aliased after MFMA

    const int t = threadIdx.x, lane = t & 63, w = t >> 6;
    const int lh = lane & 15, lq = lane >> 4;

    // bijective XCD swizzle (8192 = 8*1024); dt fastest -> X-tile L2 reuse per XCD
    const int bid = blockIdx.x;
    const int work = (bid & 7) * 1024 + (bid >> 3);
    const int pt = work >> 2, dt = work & 3;
    const int P0 = pt * 128;

    const unsigned short* xb = (const unsigned short*)xhp;
    const unsigned short* wb = (const unsigned short*)warr;

    if (t < 128) msk[t] = mask[P0 + t];

    // stage X: 32 frag units (1 KB each), linear copy; wave w takes units w*8..+8
#pragma unroll
    for (int s = 0; s < 8; ++s) {
        const int u = w * 8 + s;                         // local unit: g_loc*4+kg
        const size_t gu = ((size_t)(P0 >> 4) + (u >> 2)) * 4 + (u & 3);
        __builtin_amdgcn_global_load_lds(
            (const __attribute__((address_space(1))) unsigned*)(xb + gu * 512 + (size_t)lane * 8),
            (__attribute__((address_space(3))) unsigned*)&Xls[u * 512], 16, 0, 0);
    }
    // stage W chunk dt: 32 frag units, linear copy
#pragma unroll
    for (int s = 0; s < 8; ++s) {
        const int u = w * 8 + s;                         // local unit: rg*4+kg
        __builtin_amdgcn_global_load_lds(
            (const __attribute__((address_space(1))) unsigned*)(wb + ((size_t)dt * 32 + u) * 512 + (size_t)lane * 8),
            (__attribute__((address_space(3))) unsigned*)&Wls[u * 512], 16, 0, 0);
    }
    __syncthreads();

    // waves 2x2: wm = p-half (64p), wn = d-half (32 proj + 32 gate dims)
    const int wm = w >> 1, wn = w & 1;

    f4 acc[4][4];   // [mi][nd]: nd 0,1 = proj, 2,3 = gate
#pragma unroll
    for (int mi = 0; mi < 4; ++mi)
#pragma unroll
        for (int ni = 0; ni < 4; ++ni)
            acc[mi][ni] = (f4){0.f, 0.f, 0.f, 0.f};

#pragma unroll
    for (int kg = 0; kg < 4; ++kg) {
        s8b af[4], bfr[4];
#pragma unroll
        for (int mi = 0; mi < 4; ++mi)
            af[mi] = *(const s8b*)&Xls[(((wm * 4 + mi) * 4) + kg) * 512 + lane * 8];
#pragma unroll
        for (int nd = 0; nd < 2; ++nd) {
            bfr[nd]     = *(const s8b*)&Wls[(((wn * 2 + nd) * 4) + kg) * 512 + lane * 8];
            bfr[2 + nd] = *(const s8b*)&Wls[((((4 + wn * 2 + nd)) * 4) + kg) * 512 + lane * 8];
        }
#pragma unroll
        for (int mi = 0; mi < 4; ++mi)
#pragma unroll
            for (int ni = 0; ni < 4; ++ni)
                acc[mi][ni] = __builtin_amdgcn_mfma_f32_16x16x32_bf16(
                    af[mi], bfr[ni], acc[mi][ni], 0, 0, 0);
    }
    __syncthreads();   // all Xls/Wls reads done before tls alias writes

    // epilogue: gate + transpose tile [64 d][134 p]
#pragma unroll
    for (int mi = 0; mi < 4; ++mi)
#pragma unroll
        for (int nd = 0; nd < 2; ++nd) {
            const int dl = wn * 32 + nd * 16 + lh;
            const float pbv = proj_b[dt * 64 + dl];
            const float gbv = gate_b[dt * 64 + dl];
            const f4 P = acc[mi][nd];
            const f4 G = acc[mi][2 + nd];
            const int pbase = wm * 64 + mi * 16 + lq * 4;
            float v[4];
#pragma unroll
            for (int r = 0; r < 4; ++r)
                v[r] = msk[pbase + r] * (P[r] + pbv) * sigmoidf(G[r] + gbv);
            ushort2 u01, u23;
            u01.x = bfbits(v[0]); u01.y = bfbits(v[1]);
            u23.x = bfbits(v[2]); u23.y = bfbits(v[3]);
            *(ushort2*)&tls[dl * 134 + pbase]     = u01;
            *(ushort2*)&tls[dl * 134 + pbase + 2] = u23;
        }
    __syncthreads();

    // readout: 64 d-rows x 128 p, ushort2-coalesced (256 B / wave-instr)
    {
        __hip_bfloat16* dst0 = (dt < 2) ? lt + (size_t)(dt * 64) * TNP
                                        : rt + (size_t)((dt - 2) * 64) * TNP;
#pragma unroll
        for (int rr = 0; rr < 16; ++rr) {
            const int dl = w * 16 + rr;
            const ushort2 v = *(const ushort2*)&tls[dl * 134 + lane * 2];
            *(ushort2*)((unsigned short*)(dst0 + (size_t)dl * TNP) + P0 + lane * 2) = v;
        }
    }
}

// -------- Kernel B: per-c NT-GEMM, bf16 in/out, XCD-swizzled, LDS-transposed C --
extern "C" __global__ __launch_bounds__(256)
void k_tri_mfma(const __hip_bfloat16* __restrict__ lt,
                const __hip_bfloat16* __restrict__ rt,
                __hip_bfloat16* __restrict__ trih)
{
    __shared__ __align__(16) char smem[128 * 136 * 2];
    __hip_bfloat16* Als = (__hip_bfloat16*)smem;
    __hip_bfloat16* Bls = (__hip_bfloat16*)(smem + 8192);
    unsigned short* Cls = (unsigned short*)smem;

    const int bid = blockIdx.x;
    const int work = (bid & 7) * 256 + (bid >> 3);
    const int c = work >> 4, tt = work & 15;
    const int i0 = (tt >> 2) * 128, j0 = (tt & 3) * 128;

    const int t = threadIdx.x;
    const int w = t >> 6, lane = t & 63;
    const int wm = w >> 1, wn = w & 1;
    const int lh = lane & 15, lq = lane >> 4;

    const size_t cbase = (size_t)c * TNP;
    const int srow = lane >> 2;
    const int scol = (lane & 3) * 8;

    f4 acc[4][4];
#pragma unroll
    for (int mi = 0; mi < 4; ++mi)
#pragma unroll
        for (int ni = 0; ni < 4; ++ni)
            acc[mi][ni] = (f4){0.f, 0.f, 0.f, 0.f};

    for (int k0 = 0; k0 < TN; k0 += 32) {
        __syncthreads();
#pragma unroll
        for (int s = 0; s < 2; ++s) {
            const int r0 = w * 32 + s * 16;
            const __hip_bfloat16* ga = lt + cbase + (size_t)(i0 + r0 + srow) * TN + k0 + scol;
            const __hip_bfloat16* gb = rt + cbase + (size_t)(j0 + r0 + srow) * TN + k0 + scol;
            __builtin_amdgcn_global_load_lds(
                (const __attribute__((address_space(1))) unsigned*)ga,
                (__attribute__((address_space(3))) unsigned*)&Als[r0 * 32], 16, 0, 0);
            __builtin_amdgcn_global_load_lds(
                (const __attribute__((address_space(1))) unsigned*)gb,
                (__attribute__((address_space(3))) unsigned*)&Bls[r0 * 32], 16, 0, 0);
        }
        __syncthreads();

        s8b afr[4], bfr[4];
#pragma unroll
        for (int mi = 0; mi < 4; ++mi)
            afr[mi] = *(const s8b*)&Als[(wm * 64 + mi * 16 + lh) * 32 + lq * 8];
#pragma unroll
        for (int ni = 0; ni < 4; ++ni)
            bfr[ni] = *(const s8b*)&Bls[(wn * 64 + ni * 16 + lh) * 32 + lq * 8];
#pragma unroll
        for (int mi = 0; mi < 4; ++mi)
#pragma unroll
            for (int ni = 0; ni < 4; ++ni)
                acc[mi][ni] = __builtin_amdgcn_mfma_f32_16x16x32_bf16(
                    afr[mi], bfr[ni], acc[mi][ni], 0, 0, 0);
    }

    __syncthreads();
#pragma unroll
    for (int mi = 0; mi < 4; ++mi)
#pragma unroll
        for (int ni = 0; ni < 4; ++ni) {
            const f4 v = acc[mi][ni];
            const int jl = wn * 64 + ni * 16 + lh;
#pragma unroll
            for (int r = 0; r < 4; ++r) {
                const int il = wm * 64 + mi * 16 + lq * 4 + r;
                Cls[il * 136 + jl] = bfbits(v[r]);
            }
        }
    __syncthreads();
    {
        unsigned short* ob = (unsigned short*)trih + cbase;
#pragma unroll
        for (int qq = 0; qq < 8; ++qq) {
            const int row = qq * 16 + (t >> 4);
            const int c16 = t & 15;
            const s8b v = *(const s8b*)&Cls[row * 136 + c16 * 8];
            *(s8b*)&ob[(size_t)(i0 + row) * TN + j0 + c16 * 8] = v;
        }
    }
}

// -------- Kernel C: LN(trih) + MFMA out-proj + gl-gate (unchanged from r6) ------
constexpr int PB = 64;

extern "C" __global__ __launch_bounds__(256)
void k_out_proj(const __hip_bfloat16* __restrict__ trih,
                const __hip_bfloat16* __restrict__ xhp,
                const float* __restrict__ cnw, const float* __restrict__ cnb,
                const __hip_bfloat16* __restrict__ wcat2,
                const float* __restrict__ outp_b, const float* __restrict__ gl_b,
                float* __restrict__ outb)
{
    __shared__ unsigned short ysb[PB * 134];
    __shared__ __align__(16) unsigned short Yls[PB * TC];

    const int t = threadIdx.x, lane = t & 63, w = t >> 6;
    const int lh = lane & 15, lq = lane >> 4;
    const int P0 = blockIdx.x * PB;
    const unsigned short* tb = (const unsigned short*)trih;
    const unsigned short* xb = (const unsigned short*)xhp;
    const unsigned short* wb = (const unsigned short*)wcat2;

    {
        const int c0 = t >> 5, pp = (t & 31) * 2;
#pragma unroll
        for (int cc = 0; cc < 16; ++cc) {
            const int ch = cc * 8 + c0;
            const ushort2 v = *(const ushort2*)(tb + (size_t)ch * TNP + P0 + pp);
            ysb[pp * 134 + ch] = v.x;
            ysb[(pp + 1) * 134 + ch] = v.y;
        }
    }
    __syncthreads();

    {
        const float2 wv = ((const float2*)cnw)[lane];
        const float2 bv = ((const float2*)cnb)[lane];
        const int sw = (lane >> 2) & 7;
#pragma unroll 2
        for (int it = 0; it < 16; ++it) {
            const int pl = it * 4 + w;
            const ushort2 uv = *(const ushort2*)&ysb[pl * 134 + lane * 2];
            const float a0 = bf2f(uv.x), a1 = bf2f(uv.y);
            const float mu = wredsum(a0 + a1) * (1.0f / 128.0f);
            const float d0 = a0 - mu, d1 = a1 - mu;
            const float var = wredsum(d0 * d0 + d1 * d1) * (1.0f / 128.0f);
            const float rs = rsqrtf(var + TEPS);
            ushort2 o;
            o.x = bfbits(d0 * rs * wv.x + bv.x);
            o.y = bfbits(d1 * rs * wv.y + bv.y);
            const int chunk = ((pl >> 4) * 4 + (lane >> 4)) * 64
                            + ((lane >> 2) & 3) * 16 + ((pl & 15) ^ sw);
            *(ushort2*)&Yls[chunk * 8 + (lane & 3) * 2] = o;
        }
    }
    __syncthreads();

    const int dO = w * 32;
    const int dG = 128 + w * 32;

    f4 acc[4][4];
#pragma unroll
    for (int mi = 0; mi < 4; ++mi)
#pragma unroll
        for (int ni = 0; ni < 4; ++ni)
            acc[mi][ni] = (f4){0.f, 0.f, 0.f, 0.f};

#pragma unroll
    for (int kg = 0; kg < 4; ++kg) {
        s8b bo[2], bg[2], ay[4], ah[4];
#pragma unroll
        for (int nd = 0; nd < 2; ++nd) {
            bo[nd] = *(const s8b*)(wb + (dO + nd * 16 + lh) * TC + kg * 32 + lq * 8);
            bg[nd] = *(const s8b*)(wb + (dG + nd * 16 + lh) * TC + kg * 32 + lq * 8);
        }
        const int rsw = (kg * 4 + lq) & 7;
#pragma unroll
        for (int mi = 0; mi < 4; ++mi) {
            const int chunk = (mi * 4 + kg) * 64 + lq * 16 + (lh ^ rsw);
            ay[mi] = *(const s8b*)&Yls[chunk * 8];
            ah[mi] = *(const s8b*)(xb + (size_t)((P0 >> 4) + mi) * 2048
                                      + kg * 512 + (size_t)lane * 8);
        }
#pragma unroll
        for (int mi = 0; mi < 4; ++mi)
#pragma unroll
            for (int nd = 0; nd < 2; ++nd) {
                acc[mi][nd]     = __builtin_amdgcn_mfma_f32_16x16x32_bf16(
                    ay[mi], bo[nd], acc[mi][nd], 0, 0, 0);
                acc[mi][2 + nd] = __builtin_amdgcn_mfma_f32_16x16x32_bf16(
                    ah[mi], bg[nd], acc[mi][2 + nd], 0, 0, 0);
            }
    }

    float ob[2], gb2[2];
#pragma unroll
    for (int nd = 0; nd < 2; ++nd) {
        ob[nd]  = outp_b[w * 32 + nd * 16 + lh];
        gb2[nd] = gl_b[w * 32 + nd * 16 + lh];
    }
#pragma unroll
    for (int mi = 0; mi < 4; ++mi)
#pragma unroll
        for (int nd = 0; nd < 2; ++nd) {
            const f4 O = acc[mi][nd];
            const f4 G = acc[mi][2 + nd];
            const int d = w * 32 + nd * 16 + lh;
#pragma unroll
            for (int r = 0; r < 4; ++r) {
                const int p = P0 + mi * 16 + lq * 4 + r;
                outb[(size_t)p * TC + d] = (O[r] + ob[nd]) * sigmoidf(G[r] + gb2[nd]);
            }
        }
}

extern "C" void kernel_launch(void* const* d_in, const int* in_sizes, int n_in,
                              void* d_out, int out_size, void* d_ws, size_t ws_size,
                              hipStream_t stream)
{
    const float* act    = (const float*)d_in[0];
    const float* mask   = (const float*)d_in[1];
    const float* lnw    = (const float*)d_in[2];
    const float* lnb    = (const float*)d_in[3];
    const float* proj_w = (const float*)d_in[4];
    const float* proj_b = (const float*)d_in[5];
    const float* gate_w = (const float*)d_in[6];
    const float* gate_b = (const float*)d_in[7];
    const float* cnw    = (const float*)d_in[8];
    const float* cnb    = (const float*)d_in[9];
    const float* outp_w = (const float*)d_in[10];
    const float* outp_b = (const float*)d_in[11];
    const float* gl_w   = (const float*)d_in[12];
    const float* gl_b   = (const float*)d_in[13];

    __hip_bfloat16* lt   = (__hip_bfloat16*)d_ws;
    __hip_bfloat16* rt   = lt + (size_t)TC * TNP;
    __hip_bfloat16* xhp  = rt + (size_t)TC * TNP;
    __hip_bfloat16* trih = xhp + (size_t)TNP * TC;
    __hip_bfloat16* warr = trih + (size_t)TC * TNP;
    __hip_bfloat16* wcat2 = warr + 4 * 128 * TC;
    float* out = (float*)d_out;

    k_wconv<<<384, 256, 0, stream>>>(proj_w, gate_w, outp_w, gl_w, warr, wcat2);
    k_ln<<<TNP / 64, 256, 0, stream>>>(act, lnw, lnb, xhp);
    k_proj<<<8192, 256, 0, stream>>>(xhp, mask, warr, proj_b, gate_b, lt, rt);
    k_tri_mfma<<<2048, 256, 0, stream>>>(lt, rt, trih);
    k_out_proj<<<TNP / PB, 256, 0, stream>>>(trih, xhp, cnw, cnb, wcat2,
                                             outp_b, gl_b, out);
}

// Round 8
// 294.831 us; speedup vs baseline: 18.3851x; 1.0117x over previous
//
#include <hip/hip_runtime.h>
#include <hip/hip_bf16.h>

// Round 8: kernel C rebuilt — affine-folded LN (out = rs*(x@W') - rs*mu*S + Tb),
// p-parallel in-block stats, no Yls/swizzle/shuffle. A/B/k_tri unchanged from r7.
// ws: lt[C][NP] | rt[C][NP] | xhp (frag) | trih[C][NP] (bf16) | warr | wcat2 | S,Tb

constexpr int TN = 512;
constexpr int TC = 128;
constexpr int TNP = TN * TN;
constexpr float TEPS = 1e-5f;

typedef __attribute__((ext_vector_type(8))) short s8b;   // 8 bf16
typedef __attribute__((ext_vector_type(4))) float f4;    // 4 fp32

__device__ __forceinline__ float wredsum(float v) {
#pragma unroll
    for (int off = 32; off > 0; off >>= 1) v += __shfl_xor(v, off);
    return v;
}
__device__ __forceinline__ float sigmoidf(float x) { return 1.0f / (1.0f + __expf(-x)); }
__device__ __forceinline__ unsigned short bfbits(float f) {
    __hip_bfloat16 h = __float2bfloat16(f);
    return *reinterpret_cast<unsigned short*>(&h);
}
__device__ __forceinline__ float bf2f(unsigned short u) {
    return __uint_as_float(((unsigned int)u) << 16);
}

// xh_perm layout: unit(g = p>>4, kg = c>>5) of 512 ushorts; within unit:
// slot = lq*16 + lh (lq=(c>>3)&3, lh=p&15), elem j = c&7.
// warr frag layout: unit(nc, rg = row>>4, kg); rows<64 = proj dims, >=64 = gate.

// -------- weight pre-convert/rearrange (wcat2 proj-half folded with cnw) --------
extern "C" __global__ __launch_bounds__(256)
void k_wconv(const float* __restrict__ pw, const float* __restrict__ gw,
             const float* __restrict__ ow, const float* __restrict__ glw,
             const float* __restrict__ cnw,
             __hip_bfloat16* __restrict__ warr, __hip_bfloat16* __restrict__ wcat2)
{
    const int idx = blockIdx.x * 256 + threadIdx.x;
    if (idx < 65536) {
        const int j = idx & 7;
        const int slot = (idx >> 3) & 63;
        const int kg = (idx >> 9) & 3;
        const int rg = (idx >> 11) & 7;
        const int nc = idx >> 14;
        const int lh = slot & 15, lq = slot >> 4;
        const int row = rg * 16 + lh;
        const int k = kg * 32 + lq * 8 + j;
        const float v = (row < 64) ? pw[(nc * 64 + row) * TC + k]
                                   : gw[(nc * 64 + (row - 64)) * TC + k];
        warr[idx] = __float2bfloat16(v);
    } else if (idx < 98304) {
        const int j = idx - 65536;
        if (j < 16384) {
            const int c = j & 127;
            wcat2[j] = __float2bfloat16(cnw[c] * ow[j]);   // W' = cnw ⊙ outp_w
        } else {
            wcat2[j] = __float2bfloat16(glw[j - 16384]);
        }
    }
}

// -------- S_d / Tb_d for the affine-folded LN --------
extern "C" __global__ __launch_bounds__(128)
void k_sdt(const float* __restrict__ ow, const float* __restrict__ cnw,
           const float* __restrict__ cnb, const float* __restrict__ outp_b,
           float* __restrict__ Svec, float* __restrict__ Tbvec)
{
    const int d = threadIdx.x;
    float S = 0.f, T = 0.f;
    for (int c = 0; c < TC; ++c) {
        const float w = ow[d * TC + c];
        S += cnw[c] * w;
        T += cnb[c] * w;
    }
    Svec[d] = S;
    Tbvec[d] = T + outp_b[d];
}

// -------- Kernel A1: LayerNorm -> xh_perm (unchanged) --------
extern "C" __global__ __launch_bounds__(256)
void k_ln(const float* __restrict__ act, const float* __restrict__ lnw,
          const float* __restrict__ lnb, __hip_bfloat16* __restrict__ xhp)
{
    __shared__ __align__(16) unsigned short t16[16 * 136];
    const int t = threadIdx.x, lane = t & 63, w = t >> 6;
    const int P0 = blockIdx.x * 64;
    const float2 wv = ((const float2*)lnw)[lane];
    const float2 bv = ((const float2*)lnb)[lane];
    unsigned short* xb = (unsigned short*)xhp;

    for (int r = 0; r < 4; ++r) {
#pragma unroll
        for (int q = 0; q < 4; ++q) {
            const int prow = w * 4 + q;
            const int p = P0 + r * 16 + prow;
            const float2 a = ((const float2*)(act + (size_t)p * TC))[lane];
            const float mu = wredsum(a.x + a.y) * (1.0f / 128.0f);
            const float d0 = a.x - mu, d1 = a.y - mu;
            const float var = wredsum(d0 * d0 + d1 * d1) * (1.0f / 128.0f);
            const float rs = rsqrtf(var + TEPS);
            ushort2 o;
            o.x = bfbits(d0 * rs * wv.x + bv.x);
            o.y = bfbits(d1 * rs * wv.y + bv.y);
            *(ushort2*)&t16[prow * 136 + lane * 2] = o;
        }
        __syncthreads();
        {
            const int kg = t >> 6, lq = (t >> 4) & 3, lh = t & 15;
            const s8b v = *(const s8b*)&t16[lh * 136 + kg * 32 + lq * 8];
            *(s8b*)(xb + (size_t)((P0 >> 4) + r) * 2048 + (size_t)t * 8) = v;
        }
        __syncthreads();
    }
}

// -------- Kernel A2: MFMA proj+gate GEMM (unchanged from r7) --------
extern "C" __global__ __launch_bounds__(256)
void k_proj(const __hip_bfloat16* __restrict__ xhp, const float* __restrict__ mask,
            const __hip_bfloat16* __restrict__ warr,
            const float* __restrict__ proj_b, const float* __restrict__ gate_b,
            __hip_bfloat16* __restrict__ lt, __hip_bfloat16* __restrict__ rt)
{
    __shared__ __align__(16) unsigned short Xls[128 * TC];
    __shared__ __align__(16) unsigned short Wls[128 * TC];
    __shared__ float msk[128];
    unsigned short* tls = Xls;

    const int t = threadIdx.x, lane = t & 63, w = t >> 6;
    const int lh = lane & 15, lq = lane >> 4;

    const int bid = blockIdx.x;
    const int work = (bid & 7) * 1024 + (bid >> 3);
    const int pt = work >> 2, dt = work & 3;
    const int P0 = pt * 128;

    const unsigned short* xb = (const unsigned short*)xhp;
    const unsigned short* wb = (const unsigned short*)warr;

    if (t < 128) msk[t] = mask[P0 + t];

#pragma unroll
    for (int s = 0; s < 8; ++s) {
        const int u = w * 8 + s;
        const size_t gu = ((size_t)(P0 >> 4) + (u >> 2)) * 4 + (u & 3);
        __builtin_amdgcn_global_load_lds(
            (const __attribute__((address_space(1))) unsigned*)(xb + gu * 512 + (size_t)lane * 8),
            (__attribute__((address_space(3))) unsigned*)&Xls[u * 512], 16, 0, 0);
    }
#pragma unroll
    for (int s = 0; s < 8; ++s) {
        const int u = w * 8 + s;
        __builtin_amdgcn_global_load_lds(
            (const __attribute__((address_space(1))) unsigned*)(wb + ((size_t)dt * 32 + u) * 512 + (size_t)lane * 8),
            (__attribute__((address_space(3))) unsigned*)&Wls[u * 512], 16, 0, 0);
    }
    __syncthreads();

    const int wm = w >> 1, wn = w & 1;

    f4 acc[4][4];
#pragma unroll
    for (int mi = 0; mi < 4; ++mi)
#pragma unroll
        for (int ni = 0; ni < 4; ++ni)
            acc[mi][ni] = (f4){0.f, 0.f, 0.f, 0.f};

#pragma unroll
    for (int kg = 0; kg < 4; ++kg) {
        s8b af[4], bfr[4];
#pragma unroll
        for (int mi = 0; mi < 4; ++mi)
            af[mi] = *(const s8b*)&Xls[(((wm * 4 + mi) * 4) + kg) * 512 + lane * 8];
#pragma unroll
        for (int nd = 0; nd < 2; ++nd) {
            bfr[nd]     = *(const s8b*)&Wls[(((wn * 2 + nd) * 4) + kg) * 512 + lane * 8];
            bfr[2 + nd] = *(const s8b*)&Wls[((((4 + wn * 2 + nd)) * 4) + kg) * 512 + lane * 8];
        }
#pragma unroll
        for (int mi = 0; mi < 4; ++mi)
#pragma unroll
            for (int ni = 0; ni < 4; ++ni)
                acc[mi][ni] = __builtin_amdgcn_mfma_f32_16x16x32_bf16(
                    af[mi], bfr[ni], acc[mi][ni], 0, 0, 0);
    }
    __syncthreads();

#pragma unroll
    for (int mi = 0; mi < 4; ++mi)
#pragma unroll
        for (int nd = 0; nd < 2; ++nd) {
            const int dl = wn * 32 + nd * 16 + lh;
            const float pbv = proj_b[dt * 64 + dl];
            const float gbv = gate_b[dt * 64 + dl];
            const f4 P = acc[mi][nd];
            const f4 G = acc[mi][2 + nd];
            const int pbase = wm * 64 + mi * 16 + lq * 4;
            float v[4];
#pragma unroll
            for (int r = 0; r < 4; ++r)
                v[r] = msk[pbase + r] * (P[r] + pbv) * sigmoidf(G[r] + gbv);
            ushort2 u01, u23;
            u01.x = bfbits(v[0]); u01.y = bfbits(v[1]);
            u23.x = bfbits(v[2]); u23.y = bfbits(v[3]);
            *(ushort2*)&tls[dl * 134 + pbase]     = u01;
            *(ushort2*)&tls[dl * 134 + pbase + 2] = u23;
        }
    __syncthreads();

    {
        __hip_bfloat16* dst0 = (dt < 2) ? lt + (size_t)(dt * 64) * TNP
                                        : rt + (size_t)((dt - 2) * 64) * TNP;
#pragma unroll
        for (int rr = 0; rr < 16; ++rr) {
            const int dl = w * 16 + rr;
            const ushort2 v = *(const ushort2*)&tls[dl * 134 + lane * 2];
            *(ushort2*)((unsigned short*)(dst0 + (size_t)dl * TNP) + P0 + lane * 2) = v;
        }
    }
}

// -------- Kernel B: per-c NT-GEMM (unchanged from r7) --------
extern "C" __global__ __launch_bounds__(256)
void k_tri_mfma(const __hip_bfloat16* __restrict__ lt,
                const __hip_bfloat16* __restrict__ rt,
                __hip_bfloat16* __restrict__ trih)
{
    __shared__ __align__(16) char smem[128 * 136 * 2];
    __hip_bfloat16* Als = (__hip_bfloat16*)smem;
    __hip_bfloat16* Bls = (__hip_bfloat16*)(smem + 8192);
    unsigned short* Cls = (unsigned short*)smem;

    const int bid = blockIdx.x;
    const int work = (bid & 7) * 256 + (bid >> 3);
    const int c = work >> 4, tt = work & 15;
    const int i0 = (tt >> 2) * 128, j0 = (tt & 3) * 128;

    const int t = threadIdx.x;
    const int w = t >> 6, lane = t & 63;
    const int wm = w >> 1, wn = w & 1;
    const int lh = lane & 15, lq = lane >> 4;

    const size_t cbase = (size_t)c * TNP;
    const int srow = lane >> 2;
    const int scol = (lane & 3) * 8;

    f4 acc[4][4];
#pragma unroll
    for (int mi = 0; mi < 4; ++mi)
#pragma unroll
        for (int ni = 0; ni < 4; ++ni)
            acc[mi][ni] = (f4){0.f, 0.f, 0.f, 0.f};

    for (int k0 = 0; k0 < TN; k0 += 32) {
        __syncthreads();
#pragma unroll
        for (int s = 0; s < 2; ++s) {
            const int r0 = w * 32 + s * 16;
            const __hip_bfloat16* ga = lt + cbase + (size_t)(i0 + r0 + srow) * TN + k0 + scol;
            const __hip_bfloat16* gb = rt + cbase + (size_t)(j0 + r0 + srow) * TN + k0 + scol;
            __builtin_amdgcn_global_load_lds(
                (const __attribute__((address_space(1))) unsigned*)ga,
                (__attribute__((address_space(3))) unsigned*)&Als[r0 * 32], 16, 0, 0);
            __builtin_amdgcn_global_load_lds(
                (const __attribute__((address_space(1))) unsigned*)gb,
                (__attribute__((address_space(3))) unsigned*)&Bls[r0 * 32], 16, 0, 0);
        }
        __syncthreads();

        s8b afr[4], bfr[4];
#pragma unroll
        for (int mi = 0; mi < 4; ++mi)
            afr[mi] = *(const s8b*)&Als[(wm * 64 + mi * 16 + lh) * 32 + lq * 8];
#pragma unroll
        for (int ni = 0; ni < 4; ++ni)
            bfr[ni] = *(const s8b*)&Bls[(wn * 64 + ni * 16 + lh) * 32 + lq * 8];
#pragma unroll
        for (int mi = 0; mi < 4; ++mi)
#pragma unroll
            for (int ni = 0; ni < 4; ++ni)
                acc[mi][ni] = __builtin_amdgcn_mfma_f32_16x16x32_bf16(
                    afr[mi], bfr[ni], acc[mi][ni], 0, 0, 0);
    }

    __syncthreads();
#pragma unroll
    for (int mi = 0; mi < 4; ++mi)
#pragma unroll
        for (int ni = 0; ni < 4; ++ni) {
            const f4 v = acc[mi][ni];
            const int jl = wn * 64 + ni * 16 + lh;
#pragma unroll
            for (int r = 0; r < 4; ++r) {
                const int il = wm * 64 + mi * 16 + lq * 4 + r;
                Cls[il * 136 + jl] = bfbits(v[r]);
            }
        }
    __syncthreads();
    {
        unsigned short* ob = (unsigned short*)trih + cbase;
#pragma unroll
        for (int qq = 0; qq < 8; ++qq) {
            const int row = qq * 16 + (t >> 4);
            const int c16 = t & 15;
            const s8b v = *(const s8b*)&Cls[row * 136 + c16 * 8];
            *(s8b*)&ob[(size_t)(i0 + row) * TN + j0 + c16 * 8] = v;
        }
    }
}

// -------- Kernel C: affine-folded LN + MFMA out-proj + gl-gate --------
constexpr int PB = 64;

extern "C" __global__ __launch_bounds__(256)
void k_out_proj(const __hip_bfloat16* __restrict__ trih,
                const __hip_bfloat16* __restrict__ xhp,
                const __hip_bfloat16* __restrict__ wcat2,
                const float* __restrict__ Svec, const float* __restrict__ Tbvec,
                const float* __restrict__ gl_b,
                float* __restrict__ outb)
{
    __shared__ __align__(16) unsigned short ysb[PB * 136];   // [p][c], 16B rows
    __shared__ float2 sred[4][PB];                            // per-c-group partials
    __shared__ float2 stats[PB];                              // (mu, rs)

    const int t = threadIdx.x, lane = t & 63, w = t >> 6;
    const int lh = lane & 15, lq = lane >> 4;
    const int P0 = blockIdx.x * PB;
    const unsigned short* tb = (const unsigned short*)trih;
    const unsigned short* xb = (const unsigned short*)xhp;
    const unsigned short* wb = (const unsigned short*)wcat2;

    // ---- stage trih [c][p-tile] -> ysb[p][c] ----
    {
        const int c0 = t >> 5, pp = (t & 31) * 2;
#pragma unroll
        for (int cc = 0; cc < 16; ++cc) {
            const int ch = cc * 8 + c0;
            const ushort2 v = *(const ushort2*)(tb + (size_t)ch * TNP + P0 + pp);
            ysb[pp * 136 + ch] = v.x;
            ysb[(pp + 1) * 136 + ch] = v.y;
        }
    }
    __syncthreads();

    // ---- p-parallel stats: wave w sums c in [w*32, w*32+32) for all 64 p ----
    {
        const int pl = lane;
        float s = 0.f, s2 = 0.f;
#pragma unroll
        for (int kk = 0; kk < 4; ++kk) {
            const s8b v = *(const s8b*)&ysb[pl * 136 + w * 32 + kk * 8];
#pragma unroll
            for (int j = 0; j < 8; ++j) {
                const float f = bf2f((unsigned short)v[j]);
                s += f; s2 += f * f;
            }
        }
        sred[w][pl] = make_float2(s, s2);
    }
    __syncthreads();
    if (t < PB) {
        float s = 0.f, s2 = 0.f;
#pragma unroll
        for (int g = 0; g < 4; ++g) {
            const float2 v = sred[g][t];
            s += v.x; s2 += v.y;
        }
        const float mu = s * (1.0f / 128.0f);
        const float var = s2 * (1.0f / 128.0f) - mu * mu;
        stats[t] = make_float2(mu, rsqrtf(var + TEPS));
    }
    __syncthreads();

    // ---- dual GEMM: Y-path = raw trih frags (W' folded), H-path from xhp ----
    const int dO = w * 32;
    const int dG = 128 + w * 32;

    f4 acc[4][4];   // ni 0..1 = outp(Y·W'), 2..3 = gl(H)
#pragma unroll
    for (int mi = 0; mi < 4; ++mi)
#pragma unroll
        for (int ni = 0; ni < 4; ++ni)
            acc[mi][ni] = (f4){0.f, 0.f, 0.f, 0.f};

#pragma unroll
    for (int kg = 0; kg < 4; ++kg) {
        s8b bo[2], bg[2], ay[4], ah[4];
#pragma unroll
        for (int nd = 0; nd < 2; ++nd) {
            bo[nd] = *(const s8b*)(wb + (dO + nd * 16 + lh) * TC + kg * 32 + lq * 8);
            bg[nd] = *(const s8b*)(wb + (dG + nd * 16 + lh) * TC + kg * 32 + lq * 8);
        }
#pragma unroll
        for (int mi = 0; mi < 4; ++mi) {
            ay[mi] = *(const s8b*)&ysb[(mi * 16 + lh) * 136 + kg * 32 + lq * 8];
            ah[mi] = *(const s8b*)(xb + (size_t)((P0 >> 4) + mi) * 2048
                                      + kg * 512 + (size_t)lane * 8);
        }
#pragma unroll
        for (int mi = 0; mi < 4; ++mi)
#pragma unroll
            for (int nd = 0; nd < 2; ++nd) {
                acc[mi][nd]     = __builtin_amdgcn_mfma_f32_16x16x32_bf16(
                    ay[mi], bo[nd], acc[mi][nd], 0, 0, 0);
                acc[mi][2 + nd] = __builtin_amdgcn_mfma_f32_16x16x32_bf16(
                    ah[mi], bg[nd], acc[mi][2 + nd], 0, 0, 0);
            }
    }

    // ---- epilogue: out = rs*G - rs*mu*S_d + Tb_d, gated ----
    float Sd[2], Tbd[2], glb[2];
#pragma unroll
    for (int nd = 0; nd < 2; ++nd) {
        const int d = w * 32 + nd * 16 + lh;
        Sd[nd]  = Svec[d];
        Tbd[nd] = Tbvec[d];
        glb[nd] = gl_b[d];
    }
#pragma unroll
    for (int mi = 0; mi < 4; ++mi)
#pragma unroll
        for (int nd = 0; nd < 2; ++nd) {
            const f4 G = acc[mi][nd];
            const f4 Gg = acc[mi][2 + nd];
            const int d = w * 32 + nd * 16 + lh;
#pragma unroll
            for (int r = 0; r < 4; ++r) {
                const int ploc = mi * 16 + lq * 4 + r;
                const float2 st = stats[ploc];
                const float o = st.y * G[r] - st.y * st.x * Sd[nd] + Tbd[nd];
                outb[(size_t)(P0 + ploc) * TC + d] = o * sigmoidf(Gg[r] + glb[nd]);
            }
        }
}

extern "C" void kernel_launch(void* const* d_in, const int* in_sizes, int n_in,
                              void* d_out, int out_size, void* d_ws, size_t ws_size,
                              hipStream_t stream)
{
    const float* act    = (const float*)d_in[0];
    const float* mask   = (const float*)d_in[1];
    const float* lnw    = (const float*)d_in[2];
    const float* lnb    = (const float*)d_in[3];
    const float* proj_w = (const float*)d_in[4];
    const float* proj_b = (const float*)d_in[5];
    const float* gate_w = (const float*)d_in[6];
    const float* gate_b = (const float*)d_in[7];
    const float* cnw    = (const float*)d_in[8];
    const float* cnb    = (const float*)d_in[9];
    const float* outp_w = (const float*)d_in[10];
    const float* outp_b = (const float*)d_in[11];
    const float* gl_w   = (const float*)d_in[12];
    const float* gl_b   = (const float*)d_in[13];

    __hip_bfloat16* lt   = (__hip_bfloat16*)d_ws;
    __hip_bfloat16* rt   = lt + (size_t)TC * TNP;
    __hip_bfloat16* xhp  = rt + (size_t)TC * TNP;
    __hip_bfloat16* trih = xhp + (size_t)TNP * TC;
    __hip_bfloat16* warr = trih + (size_t)TC * TNP;
    __hip_bfloat16* wcat2 = warr + 4 * 128 * TC;
    float* Svec  = (float*)(wcat2 + 2 * TC * TC);
    float* Tbvec = Svec + TC;
    float* out = (float*)d_out;

    k_wconv<<<384, 256, 0, stream>>>(proj_w, gate_w, outp_w, gl_w, cnw, warr, wcat2);
    k_sdt<<<1, 128, 0, stream>>>(outp_w, cnw, cnb, outp_b, Svec, Tbvec);
    k_ln<<<TNP / 64, 256, 0, stream>>>(act, lnw, lnb, xhp);
    k_proj<<<8192, 256, 0, stream>>>(xhp, mask, warr, proj_b, gate_b, lt, rt);
    k_tri_mfma<<<2048, 256, 0, stream>>>(lt, rt, trih);
    k_out_proj<<<TNP / PB, 256, 0, stream>>>(trih, xhp, wcat2, Svec, Tbvec,
                                             gl_b, out);
}

// Round 9
// 288.797 us; speedup vs baseline: 18.7692x; 1.0209x over previous
//
#include <hip/hip_runtime.h>
#include <hip/hip_bf16.h>

// Round 9: kernel C LDS -> frag-unit layout (conflict-free staging/stats/frags).
// A/B/k_tri/k_ln/k_proj unchanged from r8.
// ws: lt[C][NP] | rt[C][NP] | xhp (frag) | trih[C][NP] (bf16) | warr | wcat2 | S,Tb

constexpr int TN = 512;
constexpr int TC = 128;
constexpr int TNP = TN * TN;
constexpr float TEPS = 1e-5f;

typedef __attribute__((ext_vector_type(8))) short s8b;   // 8 bf16
typedef __attribute__((ext_vector_type(4))) float f4;    // 4 fp32

__device__ __forceinline__ float wredsum(float v) {
#pragma unroll
    for (int off = 32; off > 0; off >>= 1) v += __shfl_xor(v, off);
    return v;
}
__device__ __forceinline__ float sigmoidf(float x) { return 1.0f / (1.0f + __expf(-x)); }
__device__ __forceinline__ unsigned short bfbits(float f) {
    __hip_bfloat16 h = __float2bfloat16(f);
    return *reinterpret_cast<unsigned short*>(&h);
}
__device__ __forceinline__ float bf2f(unsigned short u) {
    return __uint_as_float(((unsigned int)u) << 16);
}

// frag-unit layout (both xhp global and kernel-C LDS): unit(g = p>>4, kg = c>>5)
// of 512 ushorts; slot = ((c>>3)&3)*16 + (p&15); elem = c&7.

// -------- weight pre-convert/rearrange (wcat2 proj-half folded with cnw) --------
extern "C" __global__ __launch_bounds__(256)
void k_wconv(const float* __restrict__ pw, const float* __restrict__ gw,
             const float* __restrict__ ow, const float* __restrict__ glw,
             const float* __restrict__ cnw,
             __hip_bfloat16* __restrict__ warr, __hip_bfloat16* __restrict__ wcat2)
{
    const int idx = blockIdx.x * 256 + threadIdx.x;
    if (idx < 65536) {
        const int j = idx & 7;
        const int slot = (idx >> 3) & 63;
        const int kg = (idx >> 9) & 3;
        const int rg = (idx >> 11) & 7;
        const int nc = idx >> 14;
        const int lh = slot & 15, lq = slot >> 4;
        const int row = rg * 16 + lh;
        const int k = kg * 32 + lq * 8 + j;
        const float v = (row < 64) ? pw[(nc * 64 + row) * TC + k]
                                   : gw[(nc * 64 + (row - 64)) * TC + k];
        warr[idx] = __float2bfloat16(v);
    } else if (idx < 98304) {
        const int j = idx - 65536;
        if (j < 16384) {
            const int c = j & 127;
            wcat2[j] = __float2bfloat16(cnw[c] * ow[j]);   // W' = cnw ⊙ outp_w
        } else {
            wcat2[j] = __float2bfloat16(glw[j - 16384]);
        }
    }
}

// -------- S_d / Tb_d for the affine-folded LN --------
extern "C" __global__ __launch_bounds__(128)
void k_sdt(const float* __restrict__ ow, const float* __restrict__ cnw,
           const float* __restrict__ cnb, const float* __restrict__ outp_b,
           float* __restrict__ Svec, float* __restrict__ Tbvec)
{
    const int d = threadIdx.x;
    float S = 0.f, T = 0.f;
    for (int c = 0; c < TC; ++c) {
        const float w = ow[d * TC + c];
        S += cnw[c] * w;
        T += cnb[c] * w;
    }
    Svec[d] = S;
    Tbvec[d] = T + outp_b[d];
}

// -------- Kernel A1: LayerNorm -> xh_perm (unchanged) --------
extern "C" __global__ __launch_bounds__(256)
void k_ln(const float* __restrict__ act, const float* __restrict__ lnw,
          const float* __restrict__ lnb, __hip_bfloat16* __restrict__ xhp)
{
    __shared__ __align__(16) unsigned short t16[16 * 136];
    const int t = threadIdx.x, lane = t & 63, w = t >> 6;
    const int P0 = blockIdx.x * 64;
    const float2 wv = ((const float2*)lnw)[lane];
    const float2 bv = ((const float2*)lnb)[lane];
    unsigned short* xb = (unsigned short*)xhp;

    for (int r = 0; r < 4; ++r) {
#pragma unroll
        for (int q = 0; q < 4; ++q) {
            const int prow = w * 4 + q;
            const int p = P0 + r * 16 + prow;
            const float2 a = ((const float2*)(act + (size_t)p * TC))[lane];
            const float mu = wredsum(a.x + a.y) * (1.0f / 128.0f);
            const float d0 = a.x - mu, d1 = a.y - mu;
            const float var = wredsum(d0 * d0 + d1 * d1) * (1.0f / 128.0f);
            const float rs = rsqrtf(var + TEPS);
            ushort2 o;
            o.x = bfbits(d0 * rs * wv.x + bv.x);
            o.y = bfbits(d1 * rs * wv.y + bv.y);
            *(ushort2*)&t16[prow * 136 + lane * 2] = o;
        }
        __syncthreads();
        {
            const int kg = t >> 6, lq = (t >> 4) & 3, lh = t & 15;
            const s8b v = *(const s8b*)&t16[lh * 136 + kg * 32 + lq * 8];
            *(s8b*)(xb + (size_t)((P0 >> 4) + r) * 2048 + (size_t)t * 8) = v;
        }
        __syncthreads();
    }
}

// -------- Kernel A2: MFMA proj+gate GEMM (unchanged from r7) --------
extern "C" __global__ __launch_bounds__(256)
void k_proj(const __hip_bfloat16* __restrict__ xhp, const float* __restrict__ mask,
            const __hip_bfloat16* __restrict__ warr,
            const float* __restrict__ proj_b, const float* __restrict__ gate_b,
            __hip_bfloat16* __restrict__ lt, __hip_bfloat16* __restrict__ rt)
{
    __shared__ __align__(16) unsigned short Xls[128 * TC];
    __shared__ __align__(16) unsigned short Wls[128 * TC];
    __shared__ float msk[128];
    unsigned short* tls = Xls;

    const int t = threadIdx.x, lane = t & 63, w = t >> 6;
    const int lh = lane & 15, lq = lane >> 4;

    const int bid = blockIdx.x;
    const int work = (bid & 7) * 1024 + (bid >> 3);
    const int pt = work >> 2, dt = work & 3;
    const int P0 = pt * 128;

    const unsigned short* xb = (const unsigned short*)xhp;
    const unsigned short* wb = (const unsigned short*)warr;

    if (t < 128) msk[t] = mask[P0 + t];

#pragma unroll
    for (int s = 0; s < 8; ++s) {
        const int u = w * 8 + s;
        const size_t gu = ((size_t)(P0 >> 4) + (u >> 2)) * 4 + (u & 3);
        __builtin_amdgcn_global_load_lds(
            (const __attribute__((address_space(1))) unsigned*)(xb + gu * 512 + (size_t)lane * 8),
            (__attribute__((address_space(3))) unsigned*)&Xls[u * 512], 16, 0, 0);
    }
#pragma unroll
    for (int s = 0; s < 8; ++s) {
        const int u = w * 8 + s;
        __builtin_amdgcn_global_load_lds(
            (const __attribute__((address_space(1))) unsigned*)(wb + ((size_t)dt * 32 + u) * 512 + (size_t)lane * 8),
            (__attribute__((address_space(3))) unsigned*)&Wls[u * 512], 16, 0, 0);
    }
    __syncthreads();

    const int wm = w >> 1, wn = w & 1;

    f4 acc[4][4];
#pragma unroll
    for (int mi = 0; mi < 4; ++mi)
#pragma unroll
        for (int ni = 0; ni < 4; ++ni)
            acc[mi][ni] = (f4){0.f, 0.f, 0.f, 0.f};

#pragma unroll
    for (int kg = 0; kg < 4; ++kg) {
        s8b af[4], bfr[4];
#pragma unroll
        for (int mi = 0; mi < 4; ++mi)
            af[mi] = *(const s8b*)&Xls[(((wm * 4 + mi) * 4) + kg) * 512 + lane * 8];
#pragma unroll
        for (int nd = 0; nd < 2; ++nd) {
            bfr[nd]     = *(const s8b*)&Wls[(((wn * 2 + nd) * 4) + kg) * 512 + lane * 8];
            bfr[2 + nd] = *(const s8b*)&Wls[((((4 + wn * 2 + nd)) * 4) + kg) * 512 + lane * 8];
        }
#pragma unroll
        for (int mi = 0; mi < 4; ++mi)
#pragma unroll
            for (int ni = 0; ni < 4; ++ni)
                acc[mi][ni] = __builtin_amdgcn_mfma_f32_16x16x32_bf16(
                    af[mi], bfr[ni], acc[mi][ni], 0, 0, 0);
    }
    __syncthreads();

#pragma unroll
    for (int mi = 0; mi < 4; ++mi)
#pragma unroll
        for (int nd = 0; nd < 2; ++nd) {
            const int dl = wn * 32 + nd * 16 + lh;
            const float pbv = proj_b[dt * 64 + dl];
            const float gbv = gate_b[dt * 64 + dl];
            const f4 P = acc[mi][nd];
            const f4 G = acc[mi][2 + nd];
            const int pbase = wm * 64 + mi * 16 + lq * 4;
            float v[4];
#pragma unroll
            for (int r = 0; r < 4; ++r)
                v[r] = msk[pbase + r] * (P[r] + pbv) * sigmoidf(G[r] + gbv);
            ushort2 u01, u23;
            u01.x = bfbits(v[0]); u01.y = bfbits(v[1]);
            u23.x = bfbits(v[2]); u23.y = bfbits(v[3]);
            *(ushort2*)&tls[dl * 134 + pbase]     = u01;
            *(ushort2*)&tls[dl * 134 + pbase + 2] = u23;
        }
    __syncthreads();

    {
        __hip_bfloat16* dst0 = (dt < 2) ? lt + (size_t)(dt * 64) * TNP
                                        : rt + (size_t)((dt - 2) * 64) * TNP;
#pragma unroll
        for (int rr = 0; rr < 16; ++rr) {
            const int dl = w * 16 + rr;
            const ushort2 v = *(const ushort2*)&tls[dl * 134 + lane * 2];
            *(ushort2*)((unsigned short*)(dst0 + (size_t)dl * TNP) + P0 + lane * 2) = v;
        }
    }
}

// -------- Kernel B: per-c NT-GEMM (unchanged from r7) --------
extern "C" __global__ __launch_bounds__(256)
void k_tri_mfma(const __hip_bfloat16* __restrict__ lt,
                const __hip_bfloat16* __restrict__ rt,
                __hip_bfloat16* __restrict__ trih)
{
    __shared__ __align__(16) char smem[128 * 136 * 2];
    __hip_bfloat16* Als = (__hip_bfloat16*)smem;
    __hip_bfloat16* Bls = (__hip_bfloat16*)(smem + 8192);
    unsigned short* Cls = (unsigned short*)smem;

    const int bid = blockIdx.x;
    const int work = (bid & 7) * 256 + (bid >> 3);
    const int c = work >> 4, tt = work & 15;
    const int i0 = (tt >> 2) * 128, j0 = (tt & 3) * 128;

    const int t = threadIdx.x;
    const int w = t >> 6, lane = t & 63;
    const int wm = w >> 1, wn = w & 1;
    const int lh = lane & 15, lq = lane >> 4;

    const size_t cbase = (size_t)c * TNP;
    const int srow = lane >> 2;
    const int scol = (lane & 3) * 8;

    f4 acc[4][4];
#pragma unroll
    for (int mi = 0; mi < 4; ++mi)
#pragma unroll
        for (int ni = 0; ni < 4; ++ni)
            acc[mi][ni] = (f4){0.f, 0.f, 0.f, 0.f};

    for (int k0 = 0; k0 < TN; k0 += 32) {
        __syncthreads();
#pragma unroll
        for (int s = 0; s < 2; ++s) {
            const int r0 = w * 32 + s * 16;
            const __hip_bfloat16* ga = lt + cbase + (size_t)(i0 + r0 + srow) * TN + k0 + scol;
            const __hip_bfloat16* gb = rt + cbase + (size_t)(j0 + r0 + srow) * TN + k0 + scol;
            __builtin_amdgcn_global_load_lds(
                (const __attribute__((address_space(1))) unsigned*)ga,
                (__attribute__((address_space(3))) unsigned*)&Als[r0 * 32], 16, 0, 0);
            __builtin_amdgcn_global_load_lds(
                (const __attribute__((address_space(1))) unsigned*)gb,
                (__attribute__((address_space(3))) unsigned*)&Bls[r0 * 32], 16, 0, 0);
        }
        __syncthreads();

        s8b afr[4], bfr[4];
#pragma unroll
        for (int mi = 0; mi < 4; ++mi)
            afr[mi] = *(const s8b*)&Als[(wm * 64 + mi * 16 + lh) * 32 + lq * 8];
#pragma unroll
        for (int ni = 0; ni < 4; ++ni)
            bfr[ni] = *(const s8b*)&Bls[(wn * 64 + ni * 16 + lh) * 32 + lq * 8];
#pragma unroll
        for (int mi = 0; mi < 4; ++mi)
#pragma unroll
            for (int ni = 0; ni < 4; ++ni)
                acc[mi][ni] = __builtin_amdgcn_mfma_f32_16x16x32_bf16(
                    afr[mi], bfr[ni], acc[mi][ni], 0, 0, 0);
    }

    __syncthreads();
#pragma unroll
    for (int mi = 0; mi < 4; ++mi)
#pragma unroll
        for (int ni = 0; ni < 4; ++ni) {
            const f4 v = acc[mi][ni];
            const int jl = wn * 64 + ni * 16 + lh;
#pragma unroll
            for (int r = 0; r < 4; ++r) {
                const int il = wm * 64 + mi * 16 + lq * 4 + r;
                Cls[il * 136 + jl] = bfbits(v[r]);
            }
        }
    __syncthreads();
    {
        unsigned short* ob = (unsigned short*)trih + cbase;
#pragma unroll
        for (int qq = 0; qq < 8; ++qq) {
            const int row = qq * 16 + (t >> 4);
            const int c16 = t & 15;
            const s8b v = *(const s8b*)&Cls[row * 136 + c16 * 8];
            *(s8b*)&ob[(size_t)(i0 + row) * TN + j0 + c16 * 8] = v;
        }
    }
}

// -------- Kernel C: affine-folded LN + MFMA, frag-unit LDS (conflict-free) ------
constexpr int PB = 64;

extern "C" __global__ __launch_bounds__(256)
void k_out_proj(const __hip_bfloat16* __restrict__ trih,
                const __hip_bfloat16* __restrict__ xhp,
                const __hip_bfloat16* __restrict__ wcat2,
                const float* __restrict__ Svec, const float* __restrict__ Tbvec,
                const float* __restrict__ gl_b,
                float* __restrict__ outb)
{
    __shared__ __align__(16) unsigned short yfr[PB * TC];   // 16 KB frag units
    __shared__ float2 sred[4][PB];                           // 2 KB partials
    __shared__ float2 stats[PB];                             // (mu, rs)

    const int t = threadIdx.x, lane = t & 63, w = t >> 6;
    const int lh = lane & 15, lq = lane >> 4;
    const int P0 = blockIdx.x * PB;
    const unsigned short* tb = (const unsigned short*)trih;
    const unsigned short* xb = (const unsigned short*)xhp;
    const unsigned short* wb = (const unsigned short*)wcat2;

    // ---- stage trih [c][p] -> frag units; lane = p, wave w owns c in [32w,32w+32)
    {
        const int p = lane;
        const int ub = (p >> 4) * 4 + w;           // unit for this (p, kg=w)
        const int sl = p & 15;
#pragma unroll
        for (int ci = 0; ci < 32; ++ci) {
            const int c = w * 32 + ci;
            const unsigned short v = tb[(size_t)c * TNP + P0 + p];
            yfr[ub * 512 + (((c >> 3) & 3) * 16 + sl) * 8 + (c & 7)] = v;
        }
    }

    // ---- stats partial: wave w reduces its own kg=w chunk (wave-coherent) ----
    {
        const int p = lane;
        const int ub = (p >> 4) * 4 + w;
        float s = 0.f, s2 = 0.f;
#pragma unroll
        for (int lqc = 0; lqc < 4; ++lqc) {
            const s8b v = *(const s8b*)&yfr[ub * 512 + (lqc * 16 + (p & 15)) * 8];
#pragma unroll
            for (int j = 0; j < 8; ++j) {
                const float f = bf2f((unsigned short)v[j]);
                s += f; s2 += f * f;
            }
        }
        sred[w][p] = make_float2(s, s2);
    }
    __syncthreads();
    if (t < PB) {
        float s = 0.f, s2 = 0.f;
#pragma unroll
        for (int g = 0; g < 4; ++g) {
            const float2 v = sred[g][t];
            s += v.x; s2 += v.y;
        }
        const float mu = s * (1.0f / 128.0f);
        const float var = s2 * (1.0f / 128.0f) - mu * mu;
        stats[t] = make_float2(mu, rsqrtf(var + TEPS));
    }
    __syncthreads();

    // ---- dual GEMM: Y-frags lane-linear from yfr; H-frags from xhp global ----
    const int dO = w * 32;
    const int dG = 128 + w * 32;

    f4 acc[4][4];   // ni 0..1 = outp(Y·W'), 2..3 = gl(H)
#pragma unroll
    for (int mi = 0; mi < 4; ++mi)
#pragma unroll
        for (int ni = 0; ni < 4; ++ni)
            acc[mi][ni] = (f4){0.f, 0.f, 0.f, 0.f};

#pragma unroll
    for (int kg = 0; kg < 4; ++kg) {
        s8b bo[2], bg[2], ay[4], ah[4];
#pragma unroll
        for (int nd = 0; nd < 2; ++nd) {
            bo[nd] = *(const s8b*)(wb + (dO + nd * 16 + lh) * TC + kg * 32 + lq * 8);
            bg[nd] = *(const s8b*)(wb + (dG + nd * 16 + lh) * TC + kg * 32 + lq * 8);
        }
#pragma unroll
        for (int mi = 0; mi < 4; ++mi) {
            ay[mi] = *(const s8b*)&yfr[(mi * 4 + kg) * 512 + lane * 8];
            ah[mi] = *(const s8b*)(xb + (size_t)((P0 >> 4) + mi) * 2048
                                      + kg * 512 + (size_t)lane * 8);
        }
#pragma unroll
        for (int mi = 0; mi < 4; ++mi)
#pragma unroll
            for (int nd = 0; nd < 2; ++nd) {
                acc[mi][nd]     = __builtin_amdgcn_mfma_f32_16x16x32_bf16(
                    ay[mi], bo[nd], acc[mi][nd], 0, 0, 0);
                acc[mi][2 + nd] = __builtin_amdgcn_mfma_f32_16x16x32_bf16(
                    ah[mi], bg[nd], acc[mi][2 + nd], 0, 0, 0);
            }
    }

    // ---- epilogue: out = rs*G - rs*mu*S_d + Tb_d, gated ----
    float Sd[2], Tbd[2], glb[2];
#pragma unroll
    for (int nd = 0; nd < 2; ++nd) {
        const int d = w * 32 + nd * 16 + lh;
        Sd[nd]  = Svec[d];
        Tbd[nd] = Tbvec[d];
        glb[nd] = gl_b[d];
    }
#pragma unroll
    for (int mi = 0; mi < 4; ++mi)
#pragma unroll
        for (int nd = 0; nd < 2; ++nd) {
            const f4 G = acc[mi][nd];
            const f4 Gg = acc[mi][2 + nd];
            const int d = w * 32 + nd * 16 + lh;
#pragma unroll
            for (int r = 0; r < 4; ++r) {
                const int ploc = mi * 16 + lq * 4 + r;
                const float2 st = stats[ploc];
                const float o = st.y * G[r] - st.y * st.x * Sd[nd] + Tbd[nd];
                outb[(size_t)(P0 + ploc) * TC + d] = o * sigmoidf(Gg[r] + glb[nd]);
            }
        }
}

extern "C" void kernel_launch(void* const* d_in, const int* in_sizes, int n_in,
                              void* d_out, int out_size, void* d_ws, size_t ws_size,
                              hipStream_t stream)
{
    const float* act    = (const float*)d_in[0];
    const float* mask   = (const float*)d_in[1];
    const float* lnw    = (const float*)d_in[2];
    const float* lnb    = (const float*)d_in[3];
    const float* proj_w = (const float*)d_in[4];
    const float* proj_b = (const float*)d_in[5];
    const float* gate_w = (const float*)d_in[6];
    const float* gate_b = (const float*)d_in[7];
    const float* cnw    = (const float*)d_in[8];
    const float* cnb    = (const float*)d_in[9];
    const float* outp_w = (const float*)d_in[10];
    const float* outp_b = (const float*)d_in[11];
    const float* gl_w   = (const float*)d_in[12];
    const float* gl_b   = (const float*)d_in[13];

    __hip_bfloat16* lt   = (__hip_bfloat16*)d_ws;
    __hip_bfloat16* rt   = lt + (size_t)TC * TNP;
    __hip_bfloat16* xhp  = rt + (size_t)TC * TNP;
    __hip_bfloat16* trih = xhp + (size_t)TNP * TC;
    __hip_bfloat16* warr = trih + (size_t)TC * TNP;
    __hip_bfloat16* wcat2 = warr + 4 * 128 * TC;
    float* Svec  = (float*)(wcat2 + 2 * TC * TC);
    float* Tbvec = Svec + TC;
    float* out = (float*)d_out;

    k_wconv<<<384, 256, 0, stream>>>(proj_w, gate_w, outp_w, gl_w, cnw, warr, wcat2);
    k_sdt<<<1, 128, 0, stream>>>(outp_w, cnw, cnb, outp_b, Svec, Tbvec);
    k_ln<<<TNP / 64, 256, 0, stream>>>(act, lnw, lnb, xhp);
    k_proj<<<8192, 256, 0, stream>>>(xhp, mask, warr, proj_b, gate_b, lt, rt);
    k_tri_mfma<<<2048, 256, 0, stream>>>(lt, rt, trih);
    k_out_proj<<<TNP / PB, 256, 0, stream>>>(trih, xhp, wcat2, Svec, Tbvec,
                                             gl_b, out);
}

// Round 10
// 282.184 us; speedup vs baseline: 19.2091x; 1.0234x over previous
//
#include <hip/hip_runtime.h>
#include <hip/hip_bf16.h>

// Round 10: k_proj drops Wls (reg double-buffered W from L2, LDS 66->33KB);
// k_out_proj fuses staging+stats with b128 packed LDS writes.
// ws: lt[C][NP] | rt[C][NP] | xhp (frag) | trih[C][NP] (bf16) | warr | wcat2 | S,Tb

constexpr int TN = 512;
constexpr int TC = 128;
constexpr int TNP = TN * TN;
constexpr float TEPS = 1e-5f;

typedef __attribute__((ext_vector_type(8))) short s8b;   // 8 bf16
typedef __attribute__((ext_vector_type(4))) float f4;    // 4 fp32

__device__ __forceinline__ float wredsum(float v) {
#pragma unroll
    for (int off = 32; off > 0; off >>= 1) v += __shfl_xor(v, off);
    return v;
}
__device__ __forceinline__ float sigmoidf(float x) { return 1.0f / (1.0f + __expf(-x)); }
__device__ __forceinline__ unsigned short bfbits(float f) {
    __hip_bfloat16 h = __float2bfloat16(f);
    return *reinterpret_cast<unsigned short*>(&h);
}
__device__ __forceinline__ float bf2f(unsigned short u) {
    return __uint_as_float(((unsigned int)u) << 16);
}

// frag-unit layout (xhp global, kernel-C LDS, warr): unit(g = p>>4, kg = c>>5)
// of 512 ushorts; slot = ((c>>3)&3)*16 + (p&15); elem = c&7.

// -------- weight pre-convert/rearrange (wcat2 proj-half folded with cnw) --------
extern "C" __global__ __launch_bounds__(256)
void k_wconv(const float* __restrict__ pw, const float* __restrict__ gw,
             const float* __restrict__ ow, const float* __restrict__ glw,
             const float* __restrict__ cnw,
             __hip_bfloat16* __restrict__ warr, __hip_bfloat16* __restrict__ wcat2)
{
    const int idx = blockIdx.x * 256 + threadIdx.x;
    if (idx < 65536) {
        const int j = idx & 7;
        const int slot = (idx >> 3) & 63;
        const int kg = (idx >> 9) & 3;
        const int rg = (idx >> 11) & 7;
        const int nc = idx >> 14;
        const int lh = slot & 15, lq = slot >> 4;
        const int row = rg * 16 + lh;
        const int k = kg * 32 + lq * 8 + j;
        const float v = (row < 64) ? pw[(nc * 64 + row) * TC + k]
                                   : gw[(nc * 64 + (row - 64)) * TC + k];
        warr[idx] = __float2bfloat16(v);
    } else if (idx < 98304) {
        const int j = idx - 65536;
        if (j < 16384) {
            const int c = j & 127;
            wcat2[j] = __float2bfloat16(cnw[c] * ow[j]);   // W' = cnw ⊙ outp_w
        } else {
            wcat2[j] = __float2bfloat16(glw[j - 16384]);
        }
    }
}

// -------- S_d / Tb_d for the affine-folded LN --------
extern "C" __global__ __launch_bounds__(128)
void k_sdt(const float* __restrict__ ow, const float* __restrict__ cnw,
           const float* __restrict__ cnb, const float* __restrict__ outp_b,
           float* __restrict__ Svec, float* __restrict__ Tbvec)
{
    const int d = threadIdx.x;
    float S = 0.f, T = 0.f;
    for (int c = 0; c < TC; ++c) {
        const float w = ow[d * TC + c];
        S += cnw[c] * w;
        T += cnb[c] * w;
    }
    Svec[d] = S;
    Tbvec[d] = T + outp_b[d];
}

// -------- Kernel A1: LayerNorm -> xh_perm (unchanged) --------
extern "C" __global__ __launch_bounds__(256)
void k_ln(const float* __restrict__ act, const float* __restrict__ lnw,
          const float* __restrict__ lnb, __hip_bfloat16* __restrict__ xhp)
{
    __shared__ __align__(16) unsigned short t16[16 * 136];
    const int t = threadIdx.x, lane = t & 63, w = t >> 6;
    const int P0 = blockIdx.x * 64;
    const float2 wv = ((const float2*)lnw)[lane];
    const float2 bv = ((const float2*)lnb)[lane];
    unsigned short* xb = (unsigned short*)xhp;

    for (int r = 0; r < 4; ++r) {
#pragma unroll
        for (int q = 0; q < 4; ++q) {
            const int prow = w * 4 + q;
            const int p = P0 + r * 16 + prow;
            const float2 a = ((const float2*)(act + (size_t)p * TC))[lane];
            const float mu = wredsum(a.x + a.y) * (1.0f / 128.0f);
            const float d0 = a.x - mu, d1 = a.y - mu;
            const float var = wredsum(d0 * d0 + d1 * d1) * (1.0f / 128.0f);
            const float rs = rsqrtf(var + TEPS);
            ushort2 o;
            o.x = bfbits(d0 * rs * wv.x + bv.x);
            o.y = bfbits(d1 * rs * wv.y + bv.y);
            *(ushort2*)&t16[prow * 136 + lane * 2] = o;
        }
        __syncthreads();
        {
            const int kg = t >> 6, lq = (t >> 4) & 3, lh = t & 15;
            const s8b v = *(const s8b*)&t16[lh * 136 + kg * 32 + lq * 8];
            *(s8b*)(xb + (size_t)((P0 >> 4) + r) * 2048 + (size_t)t * 8) = v;
        }
        __syncthreads();
    }
}

// -------- Kernel A2: MFMA proj+gate GEMM; X in LDS, W reg-double-buffered ------
extern "C" __global__ __launch_bounds__(256)
void k_proj(const __hip_bfloat16* __restrict__ xhp, const float* __restrict__ mask,
            const __hip_bfloat16* __restrict__ warr,
            const float* __restrict__ proj_b, const float* __restrict__ gate_b,
            __hip_bfloat16* __restrict__ lt, __hip_bfloat16* __restrict__ rt)
{
    __shared__ __align__(16) unsigned short Xls[128 * TC];   // 32 KB, frag units
    __shared__ float msk[128];
    unsigned short* tls = Xls;   // 64x134 transpose tile aliased after MFMA

    const int t = threadIdx.x, lane = t & 63, w = t >> 6;
    const int lh = lane & 15, lq = lane >> 4;

    const int bid = blockIdx.x;
    const int work = (bid & 7) * 1024 + (bid >> 3);
    const int pt = work >> 2, dt = work & 3;
    const int P0 = pt * 128;

    const unsigned short* xb = (const unsigned short*)xhp;
    const unsigned short* wbc = (const unsigned short*)warr + (size_t)dt * 16384;

    if (t < 128) msk[t] = mask[P0 + t];

    const int wm = w >> 1, wn = w & 1;

    // stage X: 32 frag units (1 KB each), linear copy; wave w takes units w*8..+8
#pragma unroll
    for (int s = 0; s < 8; ++s) {
        const int u = w * 8 + s;
        const size_t gu = ((size_t)(P0 >> 4) + (u >> 2)) * 4 + (u & 3);
        __builtin_amdgcn_global_load_lds(
            (const __attribute__((address_space(1))) unsigned*)(xb + gu * 512 + (size_t)lane * 8),
            (__attribute__((address_space(3))) unsigned*)&Xls[u * 512], 16, 0, 0);
    }

    // W-frags kg=0 issued before the barrier (fly during X-staging drain)
    s8b bc[4], bn[4];
#pragma unroll
    for (int nd = 0; nd < 2; ++nd) {
        bc[nd]     = *(const s8b*)(wbc + (size_t)(((wn * 2 + nd) * 4) + 0) * 512 + lane * 8);
        bc[2 + nd] = *(const s8b*)(wbc + (size_t)(((4 + wn * 2 + nd) * 4) + 0) * 512 + lane * 8);
    }
    __syncthreads();

    f4 acc[4][4];   // [mi][nd]: nd 0,1 = proj, 2,3 = gate
#pragma unroll
    for (int mi = 0; mi < 4; ++mi)
#pragma unroll
        for (int ni = 0; ni < 4; ++ni)
            acc[mi][ni] = (f4){0.f, 0.f, 0.f, 0.f};

#pragma unroll
    for (int kg = 0; kg < 4; ++kg) {
        if (kg < 3) {
#pragma unroll
            for (int nd = 0; nd < 2; ++nd) {
                bn[nd]     = *(const s8b*)(wbc + (size_t)(((wn * 2 + nd) * 4) + kg + 1) * 512 + lane * 8);
                bn[2 + nd] = *(const s8b*)(wbc + (size_t)(((4 + wn * 2 + nd) * 4) + kg + 1) * 512 + lane * 8);
            }
        }
        s8b af[4];
#pragma unroll
        for (int mi = 0; mi < 4; ++mi)
            af[mi] = *(const s8b*)&Xls[(((wm * 4 + mi) * 4) + kg) * 512 + lane * 8];
#pragma unroll
        for (int mi = 0; mi < 4; ++mi)
#pragma unroll
            for (int ni = 0; ni < 4; ++ni)
                acc[mi][ni] = __builtin_amdgcn_mfma_f32_16x16x32_bf16(
                    af[mi], bc[ni], acc[mi][ni], 0, 0, 0);
        if (kg < 3) {
#pragma unroll
            for (int ni = 0; ni < 4; ++ni) bc[ni] = bn[ni];
        }
    }
    __syncthreads();   // all Xls reads done before tls alias writes

    // epilogue: gate + transpose tile [64 d][134 p]
#pragma unroll
    for (int mi = 0; mi < 4; ++mi)
#pragma unroll
        for (int nd = 0; nd < 2; ++nd) {
            const int dl = wn * 32 + nd * 16 + lh;
            const float pbv = proj_b[dt * 64 + dl];
            const float gbv = gate_b[dt * 64 + dl];
            const f4 P = acc[mi][nd];
            const f4 G = acc[mi][2 + nd];
            const int pbase = wm * 64 + mi * 16 + lq * 4;
            float v[4];
#pragma unroll
            for (int r = 0; r < 4; ++r)
                v[r] = msk[pbase + r] * (P[r] + pbv) * sigmoidf(G[r] + gbv);
            ushort2 u01, u23;
            u01.x = bfbits(v[0]); u01.y = bfbits(v[1]);
            u23.x = bfbits(v[2]); u23.y = bfbits(v[3]);
            *(ushort2*)&tls[dl * 134 + pbase]     = u01;
            *(ushort2*)&tls[dl * 134 + pbase + 2] = u23;
        }
    __syncthreads();

    // readout: 64 d-rows x 128 p, ushort2-coalesced
    {
        __hip_bfloat16* dst0 = (dt < 2) ? lt + (size_t)(dt * 64) * TNP
                                        : rt + (size_t)((dt - 2) * 64) * TNP;
#pragma unroll
        for (int rr = 0; rr < 16; ++rr) {
            const int dl = w * 16 + rr;
            const ushort2 v = *(const ushort2*)&tls[dl * 134 + lane * 2];
            *(ushort2*)((unsigned short*)(dst0 + (size_t)dl * TNP) + P0 + lane * 2) = v;
        }
    }
}

// -------- Kernel B: per-c NT-GEMM (unchanged) --------
extern "C" __global__ __launch_bounds__(256)
void k_tri_mfma(const __hip_bfloat16* __restrict__ lt,
                const __hip_bfloat16* __restrict__ rt,
                __hip_bfloat16* __restrict__ trih)
{
    __shared__ __align__(16) char smem[128 * 136 * 2];
    __hip_bfloat16* Als = (__hip_bfloat16*)smem;
    __hip_bfloat16* Bls = (__hip_bfloat16*)(smem + 8192);
    unsigned short* Cls = (unsigned short*)smem;

    const int bid = blockIdx.x;
    const int work = (bid & 7) * 256 + (bid >> 3);
    const int c = work >> 4, tt = work & 15;
    const int i0 = (tt >> 2) * 128, j0 = (tt & 3) * 128;

    const int t = threadIdx.x;
    const int w = t >> 6, lane = t & 63;
    const int wm = w >> 1, wn = w & 1;
    const int lh = lane & 15, lq = lane >> 4;

    const size_t cbase = (size_t)c * TNP;
    const int srow = lane >> 2;
    const int scol = (lane & 3) * 8;

    f4 acc[4][4];
#pragma unroll
    for (int mi = 0; mi < 4; ++mi)
#pragma unroll
        for (int ni = 0; ni < 4; ++ni)
            acc[mi][ni] = (f4){0.f, 0.f, 0.f, 0.f};

    for (int k0 = 0; k0 < TN; k0 += 32) {
        __syncthreads();
#pragma unroll
        for (int s = 0; s < 2; ++s) {
            const int r0 = w * 32 + s * 16;
            const __hip_bfloat16* ga = lt + cbase + (size_t)(i0 + r0 + srow) * TN + k0 + scol;
            const __hip_bfloat16* gb = rt + cbase + (size_t)(j0 + r0 + srow) * TN + k0 + scol;
            __builtin_amdgcn_global_load_lds(
                (const __attribute__((address_space(1))) unsigned*)ga,
                (__attribute__((address_space(3))) unsigned*)&Als[r0 * 32], 16, 0, 0);
            __builtin_amdgcn_global_load_lds(
                (const __attribute__((address_space(1))) unsigned*)gb,
                (__attribute__((address_space(3))) unsigned*)&Bls[r0 * 32], 16, 0, 0);
        }
        __syncthreads();

        s8b afr[4], bfr[4];
#pragma unroll
        for (int mi = 0; mi < 4; ++mi)
            afr[mi] = *(const s8b*)&Als[(wm * 64 + mi * 16 + lh) * 32 + lq * 8];
#pragma unroll
        for (int ni = 0; ni < 4; ++ni)
            bfr[ni] = *(const s8b*)&Bls[(wn * 64 + ni * 16 + lh) * 32 + lq * 8];
#pragma unroll
        for (int mi = 0; mi < 4; ++mi)
#pragma unroll
            for (int ni = 0; ni < 4; ++ni)
                acc[mi][ni] = __builtin_amdgcn_mfma_f32_16x16x32_bf16(
                    afr[mi], bfr[ni], acc[mi][ni], 0, 0, 0);
    }

    __syncthreads();
#pragma unroll
    for (int mi = 0; mi < 4; ++mi)
#pragma unroll
        for (int ni = 0; ni < 4; ++ni) {
            const f4 v = acc[mi][ni];
            const int jl = wn * 64 + ni * 16 + lh;
#pragma unroll
            for (int r = 0; r < 4; ++r) {
                const int il = wm * 64 + mi * 16 + lq * 4 + r;
                Cls[il * 136 + jl] = bfbits(v[r]);
            }
        }
    __syncthreads();
    {
        unsigned short* ob = (unsigned short*)trih + cbase;
#pragma unroll
        for (int qq = 0; qq < 8; ++qq) {
            const int row = qq * 16 + (t >> 4);
            const int c16 = t & 15;
            const s8b v = *(const s8b*)&Cls[row * 136 + c16 * 8];
            *(s8b*)&ob[(size_t)(i0 + row) * TN + j0 + c16 * 8] = v;
        }
    }
}

// -------- Kernel C: affine-folded LN + MFMA, fused staging+stats --------
constexpr int PB = 64;

extern "C" __global__ __launch_bounds__(256)
void k_out_proj(const __hip_bfloat16* __restrict__ trih,
                const __hip_bfloat16* __restrict__ xhp,
                const __hip_bfloat16* __restrict__ wcat2,
                const float* __restrict__ Svec, const float* __restrict__ Tbvec,
                const float* __restrict__ gl_b,
                float* __restrict__ outb)
{
    __shared__ __align__(16) unsigned short yfr[PB * TC];   // 16 KB frag units
    __shared__ float2 sred[4][PB];                           // 2 KB partials
    __shared__ float2 stats[PB];                             // (mu, rs)

    const int t = threadIdx.x, lane = t & 63, w = t >> 6;
    const int lh = lane & 15, lq = lane >> 4;
    const int P0 = blockIdx.x * PB;
    const unsigned short* tb = (const unsigned short*)trih;
    const unsigned short* xb = (const unsigned short*)xhp;
    const unsigned short* wb = (const unsigned short*)wcat2;

    // ---- fused stage+stats: lane = p, wave w owns c in [32w,32w+32) ----
    {
        const int p = lane;
        const int ub = (p >> 4) * 4 + w;
        const int sl = p & 15;
        float s = 0.f, s2 = 0.f;
#pragma unroll
        for (int q = 0; q < 4; ++q) {
            unsigned short tmp[8];
#pragma unroll
            for (int j = 0; j < 8; ++j) {
                const int c = w * 32 + q * 8 + j;
                tmp[j] = tb[(size_t)c * TNP + P0 + p];
                const float f = bf2f(tmp[j]);
                s += f; s2 += f * f;
            }
            *(s8b*)&yfr[ub * 512 + (q * 16 + sl) * 8] = *(const s8b*)tmp;
        }
        sred[w][p] = make_float2(s, s2);
    }
    __syncthreads();
    if (t < PB) {
        float s = 0.f, s2 = 0.f;
#pragma unroll
        for (int g = 0; g < 4; ++g) {
            const float2 v = sred[g][t];
            s += v.x; s2 += v.y;
        }
        const float mu = s * (1.0f / 128.0f);
        const float var = s2 * (1.0f / 128.0f) - mu * mu;
        stats[t] = make_float2(mu, rsqrtf(var + TEPS));
    }
    __syncthreads();

    // ---- dual GEMM: Y-frags lane-linear from yfr; H-frags from xhp global ----
    const int dO = w * 32;
    const int dG = 128 + w * 32;

    f4 acc[4][4];   // ni 0..1 = outp(Y·W'), 2..3 = gl(H)
#pragma unroll
    for (int mi = 0; mi < 4; ++mi)
#pragma unroll
        for (int ni = 0; ni < 4; ++ni)
            acc[mi][ni] = (f4){0.f, 0.f, 0.f, 0.f};

#pragma unroll
    for (int kg = 0; kg < 4; ++kg) {
        s8b bo[2], bg[2], ay[4], ah[4];
#pragma unroll
        for (int nd = 0; nd < 2; ++nd) {
            bo[nd] = *(const s8b*)(wb + (dO + nd * 16 + lh) * TC + kg * 32 + lq * 8);
            bg[nd] = *(const s8b*)(wb + (dG + nd * 16 + lh) * TC + kg * 32 + lq * 8);
        }
#pragma unroll
        for (int mi = 0; mi < 4; ++mi) {
            ay[mi] = *(const s8b*)&yfr[(mi * 4 + kg) * 512 + lane * 8];
            ah[mi] = *(const s8b*)(xb + (size_t)((P0 >> 4) + mi) * 2048
                                      + kg * 512 + (size_t)lane * 8);
        }
#pragma unroll
        for (int mi = 0; mi < 4; ++mi)
#pragma unroll
            for (int nd = 0; nd < 2; ++nd) {
                acc[mi][nd]     = __builtin_amdgcn_mfma_f32_16x16x32_bf16(
                    ay[mi], bo[nd], acc[mi][nd], 0, 0, 0);
                acc[mi][2 + nd] = __builtin_amdgcn_mfma_f32_16x16x32_bf16(
                    ah[mi], bg[nd], acc[mi][2 + nd], 0, 0, 0);
            }
    }

    // ---- epilogue: out = rs*G - rs*mu*S_d + Tb_d, gated ----
    float Sd[2], Tbd[2], glb[2];
#pragma unroll
    for (int nd = 0; nd < 2; ++nd) {
        const int d = w * 32 + nd * 16 + lh;
        Sd[nd]  = Svec[d];
        Tbd[nd] = Tbvec[d];
        glb[nd] = gl_b[d];
    }
#pragma unroll
    for (int mi = 0; mi < 4; ++mi)
#pragma unroll
        for (int nd = 0; nd < 2; ++nd) {
            const f4 G = acc[mi][nd];
            const f4 Gg = acc[mi][2 + nd];
            const int d = w * 32 + nd * 16 + lh;
#pragma unroll
            for (int r = 0; r < 4; ++r) {
                const int ploc = mi * 16 + lq * 4 + r;
                const float2 st = stats[ploc];
                const float o = st.y * G[r] - st.y * st.x * Sd[nd] + Tbd[nd];
                outb[(size_t)(P0 + ploc) * TC + d] = o * sigmoidf(Gg[r] + glb[nd]);
            }
        }
}

extern "C" void kernel_launch(void* const* d_in, const int* in_sizes, int n_in,
                              void* d_out, int out_size, void* d_ws, size_t ws_size,
                              hipStream_t stream)
{
    const float* act    = (const float*)d_in[0];
    const float* mask   = (const float*)d_in[1];
    const float* lnw    = (const float*)d_in[2];
    const float* lnb    = (const float*)d_in[3];
    const float* proj_w = (const float*)d_in[4];
    const float* proj_b = (const float*)d_in[5];
    const float* gate_w = (const float*)d_in[6];
    const float* gate_b = (const float*)d_in[7];
    const float* cnw    = (const float*)d_in[8];
    const float* cnb    = (const float*)d_in[9];
    const float* outp_w = (const float*)d_in[10];
    const float* outp_b = (const float*)d_in[11];
    const float* gl_w   = (const float*)d_in[12];
    const float* gl_b   = (const float*)d_in[13];

    __hip_bfloat16* lt   = (__hip_bfloat16*)d_ws;
    __hip_bfloat16* rt   = lt + (size_t)TC * TNP;
    __hip_bfloat16* xhp  = rt + (size_t)TC * TNP;
    __hip_bfloat16* trih = xhp + (size_t)TNP * TC;
    __hip_bfloat16* warr = trih + (size_t)TC * TNP;
    __hip_bfloat16* wcat2 = warr + 4 * 128 * TC;
    float* Svec  = (float*)(wcat2 + 2 * TC * TC);
    float* Tbvec = Svec + TC;
    float* out = (float*)d_out;

    k_wconv<<<384, 256, 0, stream>>>(proj_w, gate_w, outp_w, gl_w, cnw, warr, wcat2);
    k_sdt<<<1, 128, 0, stream>>>(outp_w, cnw, cnb, outp_b, Svec, Tbvec);
    k_ln<<<TNP / 64, 256, 0, stream>>>(act, lnw, lnb, xhp);
    k_proj<<<8192, 256, 0, stream>>>(xhp, mask, warr, proj_b, gate_b, lt, rt);
    k_tri_mfma<<<2048, 256, 0, stream>>>(lt, rt, trih);
    k_out_proj<<<TNP / PB, 256, 0, stream>>>(trih, xhp, wcat2, Svec, Tbvec,
                                             gl_b, out);
}